// Round 1
// baseline (1602.133 us; speedup 1.0000x reference)
//
#include <hip/hip_runtime.h>
#include <hip/hip_bf16.h>
#include <math.h>

#define T_LEN 2048
#define DIM 2048
#define CONV_DIM 2048
#define KEY_DIM 512
#define VAL_DIM 1024
#define NK 8
#define NV 16

// ---------------- GEMM: C[M,N] = A[M,K] @ W[N,K]^T  (f32, tiled) ----------------
template<int BM, int BN, int BK>
__global__ __launch_bounds__(256) void gemm_nt_f32(
    int M, int N, int K,
    const float* __restrict__ A,
    const float* __restrict__ W,
    float* __restrict__ C)
{
    __shared__ float As[BK][BM + 4];
    __shared__ float Bs[BK][BN + 4];
    const int tid = threadIdx.x;
    const int m0 = blockIdx.y * BM;
    const int n0 = blockIdx.x * BN;
    const int tx = tid & 15;
    const int ty = tid >> 4;
    const int ra = tid >> 1;           // 0..127: row within tile
    const int kc = (tid & 1) * 8;      // 0 or 8: k sub-offset

    float acc[8][8];
    #pragma unroll
    for (int i = 0; i < 8; ++i)
        #pragma unroll
        for (int j = 0; j < 8; ++j) acc[i][j] = 0.f;

    for (int k0 = 0; k0 < K; k0 += BK) {
        float4 a0 = *(const float4*)&A[(size_t)(m0 + ra) * K + k0 + kc];
        float4 a1 = *(const float4*)&A[(size_t)(m0 + ra) * K + k0 + kc + 4];
        float4 b0 = *(const float4*)&W[(size_t)(n0 + ra) * K + k0 + kc];
        float4 b1 = *(const float4*)&W[(size_t)(n0 + ra) * K + k0 + kc + 4];
        __syncthreads();   // previous compute done before LDS overwrite
        As[kc+0][ra]=a0.x; As[kc+1][ra]=a0.y; As[kc+2][ra]=a0.z; As[kc+3][ra]=a0.w;
        As[kc+4][ra]=a1.x; As[kc+5][ra]=a1.y; As[kc+6][ra]=a1.z; As[kc+7][ra]=a1.w;
        Bs[kc+0][ra]=b0.x; Bs[kc+1][ra]=b0.y; Bs[kc+2][ra]=b0.z; Bs[kc+3][ra]=b0.w;
        Bs[kc+4][ra]=b1.x; Bs[kc+5][ra]=b1.y; Bs[kc+6][ra]=b1.z; Bs[kc+7][ra]=b1.w;
        __syncthreads();
        #pragma unroll
        for (int kk = 0; kk < BK; ++kk) {
            float a[8], b[8];
            *(float4*)&a[0] = *(float4*)&As[kk][ty*8];
            *(float4*)&a[4] = *(float4*)&As[kk][ty*8+4];
            *(float4*)&b[0] = *(float4*)&Bs[kk][tx*8];
            *(float4*)&b[4] = *(float4*)&Bs[kk][tx*8+4];
            #pragma unroll
            for (int i = 0; i < 8; ++i)
                #pragma unroll
                for (int j = 0; j < 8; ++j)
                    acc[i][j] += a[i] * b[j];
        }
    }
    #pragma unroll
    for (int i = 0; i < 8; ++i) {
        size_t off = (size_t)(m0 + ty*8 + i) * N + n0 + tx*8;
        float4 c0 = make_float4(acc[i][0], acc[i][1], acc[i][2], acc[i][3]);
        float4 c1 = make_float4(acc[i][4], acc[i][5], acc[i][6], acc[i][7]);
        *(float4*)&C[off]     = c0;
        *(float4*)&C[off + 4] = c1;
    }
}

// ---------------- beta = sigmoid(x@Wb^T), g = -exp(A_log)*softplus(x@Wa^T + dt_bias) ----------------
__global__ __launch_bounds__(256) void betag_kernel(
    const float* __restrict__ x, const float* __restrict__ Wb, const float* __restrict__ Wa,
    const float* __restrict__ dt_bias, const float* __restrict__ A_log,
    float* __restrict__ beta, float* __restrict__ g)
{
    int t = blockIdx.x;
    __shared__ float xs[DIM];
    for (int i = threadIdx.x; i < DIM; i += 256) xs[i] = x[(size_t)t*DIM + i];
    __syncthreads();
    int wave = threadIdx.x >> 6, lane = threadIdx.x & 63;
    for (int o = wave; o < 2*NV; o += 4) {
        int n = o & (NV-1);
        const float* Wr = ((o < NV) ? Wb : Wa) + (size_t)n * DIM;
        float s = 0.f;
        for (int k = lane; k < DIM; k += 64) s += xs[k] * Wr[k];
        #pragma unroll
        for (int off = 1; off < 64; off <<= 1) s += __shfl_xor(s, off, 64);
        if (lane == 0) {
            if (o < NV) {
                beta[(size_t)t*NV + n] = 1.f / (1.f + expf(-s));
            } else {
                float sp = s + dt_bias[n];
                sp = (sp > 20.f) ? sp : log1pf(expf(sp));
                g[(size_t)t*NV + n] = -expf(A_log[n]) * sp;
            }
        }
    }
}

// ---------------- causal depthwise conv (K=4) + SiLU ----------------
__global__ __launch_bounds__(256) void conv_silu_kernel(
    const float* __restrict__ qkv_raw,
    const float* __restrict__ conv_w,
    float* __restrict__ qkv_act)
{
    int c = blockIdx.x * 256 + threadIdx.x;
    int t = blockIdx.y;
    float4 w = ((const float4*)conv_w)[c];   // conv_w[c][0][0..3]
    float s = 0.f;
    if (t >= 3) s += qkv_raw[(size_t)(t-3)*CONV_DIM + c] * w.x;
    if (t >= 2) s += qkv_raw[(size_t)(t-2)*CONV_DIM + c] * w.y;
    if (t >= 1) s += qkv_raw[(size_t)(t-1)*CONV_DIM + c] * w.z;
    s += qkv_raw[(size_t)t*CONV_DIM + c] * w.w;
    qkv_act[(size_t)t*CONV_DIM + c] = s / (1.f + expf(-s));   // silu
}

// ---------------- l2norm of q (scaled by dk^-0.5) and k per (t, src-head) ----------------
__global__ __launch_bounds__(256) void l2norm_qk_kernel(
    const float* __restrict__ qkv_act, float* __restrict__ qn, float* __restrict__ kn)
{
    int row = blockIdx.x * 4 + (threadIdx.x >> 6);   // t*8 + hk
    int lane = threadIdx.x & 63;
    int t = row >> 3, hk = row & 7;
    float q = qkv_act[(size_t)t*CONV_DIM + hk*64 + lane];
    float k = qkv_act[(size_t)t*CONV_DIM + KEY_DIM + hk*64 + lane];
    float sq = q*q, sk = k*k;
    #pragma unroll
    for (int off = 1; off < 64; off <<= 1) {
        sq += __shfl_xor(sq, off, 64);
        sk += __shfl_xor(sk, off, 64);
    }
    qn[(size_t)row*64 + lane] = q * rsqrtf(sq + 1e-6f) * 0.125f;  // * DK^-0.5
    kn[(size_t)row*64 + lane] = k * rsqrtf(sk + 1e-6f);
}

// ---------------- gated delta rule: sequential scan, one block per head ----------------
// Thread layout: col = tid>>2 (0..63 value dim), rg = tid&3 (row group; rows rg*16..rg*16+15).
// The 4 lanes sharing a column are consecutive -> shfl_xor(1), shfl_xor(2) reductions.
__global__ __launch_bounds__(256) void scan_kernel(
    const float* __restrict__ qn, const float* __restrict__ kn,
    const float* __restrict__ qkv_act,
    const float* __restrict__ g, const float* __restrict__ beta,
    float* __restrict__ y)
{
    const int h = blockIdx.x;      // 0..15
    const int hs = h >> 1;         // GQA source head
    const int tid = threadIdx.x;
    const int col = tid >> 2;
    const int rg  = tid & 3;

    __shared__ float qs[64][64];
    __shared__ float ks[64][64];
    __shared__ float vs[64][64];
    __shared__ float ds[64];
    __shared__ float bs[64];

    float S[16];
    #pragma unroll
    for (int i = 0; i < 16; ++i) S[i] = 0.f;

    for (int t0 = 0; t0 < T_LEN; t0 += 64) {
        __syncthreads();
        #pragma unroll
        for (int i = 0; i < 4; ++i) {
            int idx4 = tid + i*256;            // 0..1023 float4s
            int tt = idx4 >> 4;                // 0..63
            int dd = (idx4 & 15) * 4;          // 0..60
            *(float4*)&qs[tt][dd] = *(const float4*)&qn[(size_t)(t0+tt)*KEY_DIM + hs*64 + dd];
            *(float4*)&ks[tt][dd] = *(const float4*)&kn[(size_t)(t0+tt)*KEY_DIM + hs*64 + dd];
            *(float4*)&vs[tt][dd] = *(const float4*)&qkv_act[(size_t)(t0+tt)*CONV_DIM + 2*KEY_DIM + h*64 + dd];
        }
        if (tid < 64) {
            ds[tid] = expf(g[(size_t)(t0+tid)*NV + h]);
            bs[tid] = beta[(size_t)(t0+tid)*NV + h];
        }
        __syncthreads();

        for (int t = 0; t < 64; ++t) {
            float decay = ds[t];
            float bt = bs[t];
            float kv[16], qv[16];
            #pragma unroll
            for (int i = 0; i < 16; i += 4) {
                *(float4*)&kv[i] = *(float4*)&ks[t][rg*16 + i];
                *(float4*)&qv[i] = *(float4*)&qs[t][rg*16 + i];
            }
            float p0=0.f,p1=0.f,p2=0.f,p3=0.f;
            #pragma unroll
            for (int i = 0; i < 16; i += 4) {
                S[i]   *= decay; p0 += S[i]  *kv[i];
                S[i+1] *= decay; p1 += S[i+1]*kv[i+1];
                S[i+2] *= decay; p2 += S[i+2]*kv[i+2];
                S[i+3] *= decay; p3 += S[i+3]*kv[i+3];
            }
            float p = (p0+p1)+(p2+p3);
            p += __shfl_xor(p, 1, 64);
            p += __shfl_xor(p, 2, 64);
            float delta = (vs[t][col] - p) * bt;
            float o0=0.f,o1=0.f,o2=0.f,o3=0.f;
            #pragma unroll
            for (int i = 0; i < 16; i += 4) {
                S[i]   += kv[i]  *delta; o0 += S[i]  *qv[i];
                S[i+1] += kv[i+1]*delta; o1 += S[i+1]*qv[i+1];
                S[i+2] += kv[i+2]*delta; o2 += S[i+2]*qv[i+2];
                S[i+3] += kv[i+3]*delta; o3 += S[i+3]*qv[i+3];
            }
            float o = (o0+o1)+(o2+o3);
            o += __shfl_xor(o, 1, 64);
            o += __shfl_xor(o, 2, 64);
            if (rg == 0) y[(size_t)(t0+t)*VAL_DIM + h*64 + col] = o;
        }
    }
}

// ---------------- RMSNorm(dv) * norm_weight * silu(z) ----------------
__global__ __launch_bounds__(256) void rmsnorm_gate_kernel(
    const float* __restrict__ y, const float* __restrict__ z,
    const float* __restrict__ nw, float* __restrict__ yn)
{
    int row = blockIdx.x * 4 + (threadIdx.x >> 6);   // t*16 + h
    int lane = threadIdx.x & 63;
    float v = y[(size_t)row*64 + lane];
    float ss = v*v;
    #pragma unroll
    for (int off = 1; off < 64; off <<= 1) ss += __shfl_xor(ss, off, 64);
    float rn = rsqrtf(ss * (1.f/64.f) + 1e-6f);
    float zz = z[(size_t)row*64 + lane];
    yn[(size_t)row*64 + lane] = nw[lane] * v * rn * (zz / (1.f + expf(-zz)));
}

extern "C" void kernel_launch(void* const* d_in, const int* in_sizes, int n_in,
                              void* d_out, int out_size, void* d_ws, size_t ws_size,
                              hipStream_t stream)
{
    const float* x      = (const float*)d_in[0];
    const float* W_qkv  = (const float*)d_in[1];
    const float* W_z    = (const float*)d_in[2];
    const float* W_b    = (const float*)d_in[3];
    const float* W_a    = (const float*)d_in[4];
    const float* W_out  = (const float*)d_in[5];
    const float* conv_w = (const float*)d_in[6];
    const float* dt_b   = (const float*)d_in[7];
    const float* A_log  = (const float*)d_in[8];
    const float* nw     = (const float*)d_in[9];
    float* out = (float*)d_out;

    float* ws = (float*)d_ws;
    const size_t M1 = 1u << 20;
    float* qkv_raw = ws;                       // 4M floats
    float* y_buf   = ws;                       // 2M (reuses qkv_raw after conv)
    float* yn_buf  = ws + 2*M1;                // 2M
    float* qkv_act = ws + 4*M1;                // 4M
    float* z_buf   = ws + 8*M1;                // 2M
    float* beta    = ws + 10*M1;               // 32K
    float* g_buf   = ws + 10*M1 + 32768;       // 32K
    float* qn      = ws + 10*M1 + 65536;       // 1M
    float* kn      = ws + 11*M1 + 65536;       // 1M

    dim3 blk(256);
    // 1) qkv = x @ W_qkv^T
    gemm_nt_f32<128,128,16><<<dim3(CONV_DIM/128, T_LEN/128), blk, 0, stream>>>(
        T_LEN, CONV_DIM, DIM, x, W_qkv, qkv_raw);
    // 2) z = x @ W_z^T
    gemm_nt_f32<128,128,16><<<dim3(VAL_DIM/128, T_LEN/128), blk, 0, stream>>>(
        T_LEN, VAL_DIM, DIM, x, W_z, z_buf);
    // 3) beta, g
    betag_kernel<<<dim3(T_LEN), blk, 0, stream>>>(x, W_b, W_a, dt_b, A_log, beta, g_buf);
    // 4) causal depthwise conv + silu
    conv_silu_kernel<<<dim3(CONV_DIM/256, T_LEN), blk, 0, stream>>>(qkv_raw, conv_w, qkv_act);
    // 5) l2norm q/k
    l2norm_qk_kernel<<<dim3(T_LEN*NK/4), blk, 0, stream>>>(qkv_act, qn, kn);
    // 6) gated delta rule scan
    scan_kernel<<<dim3(NV), blk, 0, stream>>>(qn, kn, qkv_act, g_buf, beta, y_buf);
    // 7) RMSNorm + gate
    rmsnorm_gate_kernel<<<dim3(T_LEN*NV/4), blk, 0, stream>>>(y_buf, z_buf, nw, yn_buf);
    // 8) out = yn @ W_out^T
    gemm_nt_f32<128,128,16><<<dim3(DIM/128, T_LEN/128), blk, 0, stream>>>(
        T_LEN, DIM, VAL_DIM, yn_buf, W_out, out);
}

// Round 2
// 1052.859 us; speedup vs baseline: 1.5217x; 1.5217x over previous
//
#include <hip/hip_runtime.h>
#include <hip/hip_bf16.h>
#include <math.h>

#define T_LEN 2048
#define DIM 2048
#define CONV_DIM 2048
#define KEY_DIM 512
#define VAL_DIM 1024
#define NK 8
#define NV 16
#define NCHUNK 32

// ---------------- helpers ----------------
static __device__ __forceinline__ void unpack8(uint4 raw, float* dst) {
    dst[0] = __uint_as_float(raw.x << 16);
    dst[1] = __uint_as_float(raw.x & 0xffff0000u);
    dst[2] = __uint_as_float(raw.y << 16);
    dst[3] = __uint_as_float(raw.y & 0xffff0000u);
    dst[4] = __uint_as_float(raw.z << 16);
    dst[5] = __uint_as_float(raw.z & 0xffff0000u);
    dst[6] = __uint_as_float(raw.w << 16);
    dst[7] = __uint_as_float(raw.w & 0xffff0000u);
}
static __device__ __forceinline__ unsigned short f2bf(float f) {
    unsigned int u = __float_as_uint(f);
    unsigned int r = (u + 0x7fffu + ((u >> 16) & 1u)) >> 16;
    return (unsigned short)r;
}
static __device__ __forceinline__ void store_bf16x4(__hip_bfloat16* dst, float a, float b, float c, float d) {
    union { unsigned short h[4]; uint2 u; } p;
    p.h[0] = f2bf(a); p.h[1] = f2bf(b); p.h[2] = f2bf(c); p.h[3] = f2bf(d);
    *(uint2*)dst = p.u;
}

// ---------------- GEMM: C[M,N] = A[M,K] @ W[N,K]^T  (f32, tiled) ----------------
template<int BM, int BN, int BK>
__global__ __launch_bounds__(256) void gemm_nt_f32(
    int M, int N, int K,
    const float* __restrict__ A,
    const float* __restrict__ W,
    float* __restrict__ C)
{
    __shared__ float As[BK][BM + 4];
    __shared__ float Bs[BK][BN + 4];
    const int tid = threadIdx.x;
    const int m0 = blockIdx.y * BM;
    const int n0 = blockIdx.x * BN;
    const int tx = tid & 15;
    const int ty = tid >> 4;
    const int ra = tid >> 1;
    const int kc = (tid & 1) * 8;

    float acc[8][8];
    #pragma unroll
    for (int i = 0; i < 8; ++i)
        #pragma unroll
        for (int j = 0; j < 8; ++j) acc[i][j] = 0.f;

    for (int k0 = 0; k0 < K; k0 += BK) {
        float4 a0 = *(const float4*)&A[(size_t)(m0 + ra) * K + k0 + kc];
        float4 a1 = *(const float4*)&A[(size_t)(m0 + ra) * K + k0 + kc + 4];
        float4 b0 = *(const float4*)&W[(size_t)(n0 + ra) * K + k0 + kc];
        float4 b1 = *(const float4*)&W[(size_t)(n0 + ra) * K + k0 + kc + 4];
        __syncthreads();
        As[kc+0][ra]=a0.x; As[kc+1][ra]=a0.y; As[kc+2][ra]=a0.z; As[kc+3][ra]=a0.w;
        As[kc+4][ra]=a1.x; As[kc+5][ra]=a1.y; As[kc+6][ra]=a1.z; As[kc+7][ra]=a1.w;
        Bs[kc+0][ra]=b0.x; Bs[kc+1][ra]=b0.y; Bs[kc+2][ra]=b0.z; Bs[kc+3][ra]=b0.w;
        Bs[kc+4][ra]=b1.x; Bs[kc+5][ra]=b1.y; Bs[kc+6][ra]=b1.z; Bs[kc+7][ra]=b1.w;
        __syncthreads();
        #pragma unroll
        for (int kk = 0; kk < BK; ++kk) {
            float a[8], b[8];
            *(float4*)&a[0] = *(float4*)&As[kk][ty*8];
            *(float4*)&a[4] = *(float4*)&As[kk][ty*8+4];
            *(float4*)&b[0] = *(float4*)&Bs[kk][tx*8];
            *(float4*)&b[4] = *(float4*)&Bs[kk][tx*8+4];
            #pragma unroll
            for (int i = 0; i < 8; ++i)
                #pragma unroll
                for (int j = 0; j < 8; ++j)
                    acc[i][j] += a[i] * b[j];
        }
    }
    #pragma unroll
    for (int i = 0; i < 8; ++i) {
        size_t off = (size_t)(m0 + ty*8 + i) * N + n0 + tx*8;
        *(float4*)&C[off]     = make_float4(acc[i][0], acc[i][1], acc[i][2], acc[i][3]);
        *(float4*)&C[off + 4] = make_float4(acc[i][4], acc[i][5], acc[i][6], acc[i][7]);
    }
}

// ---------------- beta/g ----------------
__global__ __launch_bounds__(256) void betag_kernel(
    const float* __restrict__ x, const float* __restrict__ Wb, const float* __restrict__ Wa,
    const float* __restrict__ dt_bias, const float* __restrict__ A_log,
    float* __restrict__ beta, float* __restrict__ g)
{
    int t = blockIdx.x;
    __shared__ float xs[DIM];
    for (int i = threadIdx.x; i < DIM; i += 256) xs[i] = x[(size_t)t*DIM + i];
    __syncthreads();
    int wave = threadIdx.x >> 6, lane = threadIdx.x & 63;
    for (int o = wave; o < 2*NV; o += 4) {
        int n = o & (NV-1);
        const float* Wr = ((o < NV) ? Wb : Wa) + (size_t)n * DIM;
        float s = 0.f;
        for (int k = lane; k < DIM; k += 64) s += xs[k] * Wr[k];
        #pragma unroll
        for (int off = 1; off < 64; off <<= 1) s += __shfl_xor(s, off, 64);
        if (lane == 0) {
            if (o < NV) {
                beta[(size_t)t*NV + n] = 1.f / (1.f + expf(-s));
            } else {
                float sp = s + dt_bias[n];
                sp = (sp > 20.f) ? sp : log1pf(expf(sp));
                g[(size_t)t*NV + n] = -expf(A_log[n]) * sp;
            }
        }
    }
}

// ---------------- causal depthwise conv (K=4) + SiLU ----------------
__global__ __launch_bounds__(256) void conv_silu_kernel(
    const float* __restrict__ qkv_raw,
    const float* __restrict__ conv_w,
    float* __restrict__ qkv_act)
{
    int c = blockIdx.x * 256 + threadIdx.x;
    int t = blockIdx.y;
    float4 w = ((const float4*)conv_w)[c];
    float s = 0.f;
    if (t >= 3) s += qkv_raw[(size_t)(t-3)*CONV_DIM + c] * w.x;
    if (t >= 2) s += qkv_raw[(size_t)(t-2)*CONV_DIM + c] * w.y;
    if (t >= 1) s += qkv_raw[(size_t)(t-1)*CONV_DIM + c] * w.z;
    s += qkv_raw[(size_t)t*CONV_DIM + c] * w.w;
    qkv_act[(size_t)t*CONV_DIM + c] = s / (1.f + expf(-s));
}

// ---------------- Phase 1: per (head, chunk) WY factors -> P, B, R, Oin ----------------
// block = h*32 + c. Outputs (per head-chunk, 64x64):
//  PT (transposed P, f32), B (bf16), RT (transposed R, f32), Oin (bf16)
__global__ __launch_bounds__(256) void phase1_kernel(
    const float* __restrict__ qkv_act,
    const float* __restrict__ g, const float* __restrict__ beta,
    float* __restrict__ PT_all, __hip_bfloat16* __restrict__ B_all,
    float* __restrict__ RT_all, __hip_bfloat16* __restrict__ Oin_all)
{
    const int hc = blockIdx.x;
    const int h = hc >> 5, c = hc & 31;
    const int hs = h >> 1;
    const int tid = threadIdx.x;
    const int t0 = c * 64;

    __shared__ float Kb[64][68];
    __shared__ float Vb[64][68];   // V, then Vt in place
    __shared__ float Qb[64][68];
    __shared__ float Ab[64][68];   // A, then W
    __shared__ float Tb[64][68];   // T, then MT
    __shared__ float gam[64], w1[64], w2[64], sce[64], eg[64];
    __shared__ float eC_s;

    // ---- load Q,K,V chunk ----
    #pragma unroll
    for (int r = 0; r < 4; ++r) {
        int id = tid + r*256;
        int row = id >> 4;
        int dq = (id & 15) * 4;
        const float* src = &qkv_act[(size_t)(t0+row)*CONV_DIM];
        *(float4*)&Qb[row][dq] = *(const float4*)&src[hs*64 + dq];
        *(float4*)&Kb[row][dq] = *(const float4*)&src[KEY_DIM + hs*64 + dq];
        *(float4*)&Vb[row][dq] = *(const float4*)&src[2*KEY_DIM + h*64 + dq];
    }
    __syncthreads();

    // ---- l2norm Q (x 1/8), K in place: 4 threads per row ----
    {
        int row = tid >> 2, q4 = (tid & 3) * 16;
        float sq = 0.f, sk = 0.f;
        #pragma unroll
        for (int d = 0; d < 16; d += 4) {
            float4 qv = *(float4*)&Qb[row][q4+d];
            float4 kv = *(float4*)&Kb[row][q4+d];
            sq += qv.x*qv.x + qv.y*qv.y + qv.z*qv.z + qv.w*qv.w;
            sk += kv.x*kv.x + kv.y*kv.y + kv.z*kv.z + kv.w*kv.w;
        }
        sq += __shfl_xor(sq, 1, 64); sq += __shfl_xor(sq, 2, 64);
        sk += __shfl_xor(sk, 1, 64); sk += __shfl_xor(sk, 2, 64);
        float rq = rsqrtf(sq + 1e-6f) * 0.125f;
        float rk = rsqrtf(sk + 1e-6f);
        #pragma unroll
        for (int d = 0; d < 16; d += 4) {
            float4 qv = *(float4*)&Qb[row][q4+d];
            qv.x*=rq; qv.y*=rq; qv.z*=rq; qv.w*=rq;
            *(float4*)&Qb[row][q4+d] = qv;
            float4 kv = *(float4*)&Kb[row][q4+d];
            kv.x*=rk; kv.y*=rk; kv.z*=rk; kv.w*=rk;
            *(float4*)&Kb[row][q4+d] = kv;
        }
    }
    // ---- gamma (inclusive cumsum of g), weights ----
    if (tid < 64) {
        float gv = g[(size_t)(t0+tid)*NV + h];
        float bv = beta[(size_t)(t0+tid)*NV + h];
        #pragma unroll
        for (int off = 1; off < 64; off <<= 1) {
            float n = __shfl_up(gv, off, 64);
            if (tid >= off) gv += n;
        }
        gam[tid] = gv;
        float e = expf(gv);
        eg[tid] = e;
        w1[tid] = bv * e;
        w2[tid] = bv;
        float gC = __shfl(gv, 63, 64);
        sce[tid] = expf(gC - gv);
        if (tid == 63) eC_s = e;
    }
    __syncthreads();

    // ---- A = beta_i e^{gi-gj} (k_i . k_j), j<i (lower tiles only) ----
    {
        int ti = tid >> 4, tj = tid & 15;
        if (tj <= ti) {
            float acc[4][4] = {};
            for (int d4 = 0; d4 < 16; ++d4) {
                float ki[4][4], kj[4][4];
                #pragma unroll
                for (int r = 0; r < 4; ++r) {
                    float4 a = *(float4*)&Kb[4*ti+r][4*d4];
                    ki[r][0]=a.x; ki[r][1]=a.y; ki[r][2]=a.z; ki[r][3]=a.w;
                    float4 b = *(float4*)&Kb[4*tj+r][4*d4];
                    kj[r][0]=b.x; kj[r][1]=b.y; kj[r][2]=b.z; kj[r][3]=b.w;
                }
                #pragma unroll
                for (int r = 0; r < 4; ++r)
                    #pragma unroll
                    for (int s = 0; s < 4; ++s)
                        #pragma unroll
                        for (int d = 0; d < 4; ++d)
                            acc[r][s] += ki[r][d]*kj[s][d];
            }
            #pragma unroll
            for (int r = 0; r < 4; ++r) {
                int ii = 4*ti + r;
                float o[4];
                #pragma unroll
                for (int s = 0; s < 4; ++s) {
                    int jj = 4*tj + s;
                    o[s] = (jj < ii) ? acc[r][s]*w2[ii]*expf(gam[ii]-gam[jj]) : 0.f;
                }
                *(float4*)&Ab[ii][4*tj] = make_float4(o[0],o[1],o[2],o[3]);
            }
        }
    }
    // ---- T init = I ----
    #pragma unroll
    for (int r = 0; r < 4; ++r) {
        int id = tid + r*256;
        int row = id >> 4, dq = (id & 15)*4;
        *(float4*)&Tb[row][dq] = make_float4(row==dq?1.f:0.f, row==dq+1?1.f:0.f,
                                             row==dq+2?1.f:0.f, row==dq+3?1.f:0.f);
    }
    __syncthreads();
    // ---- T = (I+A)^-1 : forward substitution, wave 0, lane = column ----
    if (tid < 64) {
        int col = tid;
        for (int i = 1; i < 64; ++i) {
            float acc = 0.f;
            int nj4 = (i + 3) >> 2;
            for (int j4 = 0; j4 < nj4; ++j4) {
                float4 a = *(float4*)&Ab[i][4*j4];
                int j = 4*j4;
                acc += a.x * Tb[j  ][col];
                acc += a.y * Tb[j+1][col];
                acc += a.z * Tb[j+2][col];
                acc += a.w * Tb[j+3][col];
            }
            Tb[i][col] = ((i==col)?1.f:0.f) - acc;
        }
    }
    __syncthreads();

    // ---- W = T diag(beta e^g) K  (into Ab) ----
    {
        int ti = tid >> 4, td = tid & 15;
        float acc[4][4] = {};
        for (int j4 = 0; j4 <= ti; ++j4) {
            float tr[4][4];
            #pragma unroll
            for (int r = 0; r < 4; ++r) {
                float4 a = *(float4*)&Tb[4*ti+r][4*j4];
                tr[r][0]=a.x; tr[r][1]=a.y; tr[r][2]=a.z; tr[r][3]=a.w;
            }
            float4 wv4 = *(float4*)&w1[4*j4];
            float wv[4] = {wv4.x, wv4.y, wv4.z, wv4.w};
            #pragma unroll
            for (int s = 0; s < 4; ++s) {
                float4 kr = *(float4*)&Kb[4*j4+s][4*td];
                #pragma unroll
                for (int r = 0; r < 4; ++r) {
                    float tw = tr[r][s]*wv[s];
                    acc[r][0] += tw*kr.x; acc[r][1] += tw*kr.y;
                    acc[r][2] += tw*kr.z; acc[r][3] += tw*kr.w;
                }
            }
        }
        #pragma unroll
        for (int r = 0; r < 4; ++r)
            *(float4*)&Ab[4*ti+r][4*td] = make_float4(acc[r][0],acc[r][1],acc[r][2],acc[r][3]);
    }
    __syncthreads();

    // ---- Vt = T diag(beta) V, in place (blocked bottom-up) ----
    {
        int il = tid >> 4, td = tid & 15;
        for (int blk = 3; blk >= 0; --blk) {
            int i = blk*16 + il;
            float a0=0.f,a1=0.f,a2=0.f,a3=0.f;
            int nj4 = i >> 2;
            for (int j4 = 0; j4 <= nj4; ++j4) {
                float4 tr4 = *(float4*)&Tb[i][4*j4];
                float tr[4] = {tr4.x,tr4.y,tr4.z,tr4.w};
                float4 wv4 = *(float4*)&w2[4*j4];
                float wv[4] = {wv4.x,wv4.y,wv4.z,wv4.w};
                #pragma unroll
                for (int s = 0; s < 4; ++s) {
                    float tw = tr[s]*wv[s];
                    float4 vr = *(float4*)&Vb[4*j4+s][4*td];
                    a0 += tw*vr.x; a1 += tw*vr.y; a2 += tw*vr.z; a3 += tw*vr.w;
                }
            }
            __syncthreads();
            *(float4*)&Vb[i][4*td] = make_float4(a0,a1,a2,a3);
            __syncthreads();
        }
    }

    // ---- MT[j][i] = e^{gi-gj} (q_i . k_j), i>=j  (into Tb) ----
    {
        int tj = tid >> 4, ti_ = tid & 15;
        if (ti_ >= tj) {
            float acc[4][4] = {};
            for (int d4 = 0; d4 < 16; ++d4) {
                float kj[4][4], qi[4][4];
                #pragma unroll
                for (int r = 0; r < 4; ++r) {
                    float4 a = *(float4*)&Kb[4*tj+r][4*d4];
                    kj[r][0]=a.x; kj[r][1]=a.y; kj[r][2]=a.z; kj[r][3]=a.w;
                    float4 b = *(float4*)&Qb[4*ti_+r][4*d4];
                    qi[r][0]=b.x; qi[r][1]=b.y; qi[r][2]=b.z; qi[r][3]=b.w;
                }
                #pragma unroll
                for (int r = 0; r < 4; ++r)
                    #pragma unroll
                    for (int s = 0; s < 4; ++s)
                        #pragma unroll
                        for (int d = 0; d < 4; ++d)
                            acc[r][s] += kj[r][d]*qi[s][d];
            }
            #pragma unroll
            for (int r = 0; r < 4; ++r) {
                int jj = 4*tj + r;
                float o[4];
                #pragma unroll
                for (int s = 0; s < 4; ++s) {
                    int ii = 4*ti_ + s;
                    o[s] = (ii >= jj) ? acc[r][s]*expf(gam[ii]-gam[jj]) : 0.f;
                }
                *(float4*)&Tb[jj][4*ti_] = make_float4(o[0],o[1],o[2],o[3]);
            }
        }
    }
    __syncthreads();

    const size_t obase = (size_t)(h*NCHUNK + c) * 4096;

    // ---- P[d1][d2] = eC*I - sum_i sce_i K[i][d1] W[i][d2]  -> PT (transposed) ----
    {
        int t2 = tid >> 4, t1 = tid & 15;
        float acc[4][4] = {};
        for (int i = 0; i < 64; ++i) {
            float sc = sce[i];
            float4 k4 = *(float4*)&Kb[i][4*t1];
            float ks[4] = {k4.x*sc, k4.y*sc, k4.z*sc, k4.w*sc};
            float4 w4 = *(float4*)&Ab[i][4*t2];
            float wr[4] = {w4.x,w4.y,w4.z,w4.w};
            #pragma unroll
            for (int r = 0; r < 4; ++r)
                #pragma unroll
                for (int s = 0; s < 4; ++s)
                    acc[r][s] += ks[r]*wr[s];
        }
        float eC = eC_s;
        float* Pdst = PT_all + obase;
        #pragma unroll
        for (int s = 0; s < 4; ++s) {
            int d2 = 4*t2 + s;
            float o[4];
            #pragma unroll
            for (int r = 0; r < 4; ++r) {
                int d1 = 4*t1 + r;
                o[r] = ((d1==d2) ? eC : 0.f) - acc[r][s];
            }
            *(float4*)&Pdst[(size_t)d2*64 + 4*t1] = make_float4(o[0],o[1],o[2],o[3]);
        }
    }
    // ---- B[d][v] = sum_i sce_i K[i][d] Vt[i][v]  (bf16) ----
    {
        int td = tid >> 4, tv = tid & 15;
        float acc[4][4] = {};
        for (int i = 0; i < 64; ++i) {
            float sc = sce[i];
            float4 k4 = *(float4*)&Kb[i][4*td];
            float ks[4] = {k4.x*sc, k4.y*sc, k4.z*sc, k4.w*sc};
            float4 v4 = *(float4*)&Vb[i][4*tv];
            float vt[4] = {v4.x,v4.y,v4.z,v4.w};
            #pragma unroll
            for (int r = 0; r < 4; ++r)
                #pragma unroll
                for (int s = 0; s < 4; ++s)
                    acc[r][s] += ks[r]*vt[s];
        }
        __hip_bfloat16* Bdst = B_all + obase;
        #pragma unroll
        for (int r = 0; r < 4; ++r)
            store_bf16x4(&Bdst[(size_t)(4*td+r)*64 + 4*tv], acc[r][0],acc[r][1],acc[r][2],acc[r][3]);
    }
    // ---- R[i][d] = eg_i Q[i][d] - sum_{j<=i} MT[j][i] W[j][d]  -> RT (transposed) ----
    {
        int td = tid >> 4, ti = tid & 15;
        float acc[4][4] = {};
        for (int j4 = 0; j4 <= ti; ++j4) {
            #pragma unroll
            for (int jj = 0; jj < 4; ++jj) {
                int j = 4*j4 + jj;
                float4 m4 = *(float4*)&Tb[j][4*ti];
                float mr[4] = {m4.x,m4.y,m4.z,m4.w};
                float4 w4 = *(float4*)&Ab[j][4*td];
                float wr[4] = {w4.x,w4.y,w4.z,w4.w};
                #pragma unroll
                for (int r = 0; r < 4; ++r)
                    #pragma unroll
                    for (int s = 0; s < 4; ++s)
                        acc[r][s] += mr[r]*wr[s];
            }
        }
        float val[4][4];
        #pragma unroll
        for (int r = 0; r < 4; ++r) {
            int i = 4*ti + r;
            float e = eg[i];
            float4 q4 = *(float4*)&Qb[i][4*td];
            val[r][0] = e*q4.x - acc[r][0];
            val[r][1] = e*q4.y - acc[r][1];
            val[r][2] = e*q4.z - acc[r][2];
            val[r][3] = e*q4.w - acc[r][3];
        }
        float* Rdst = RT_all + obase;
        #pragma unroll
        for (int s = 0; s < 4; ++s)
            *(float4*)&Rdst[(size_t)(4*td+s)*64 + 4*ti] = make_float4(val[0][s],val[1][s],val[2][s],val[3][s]);
    }
    // ---- Oin[i][v] = sum_{j<=i} MT[j][i] Vt[j][v]  (bf16) ----
    {
        int ti = tid >> 4, tv = tid & 15;
        float acc[4][4] = {};
        for (int j4 = 0; j4 <= ti; ++j4) {
            #pragma unroll
            for (int jj = 0; jj < 4; ++jj) {
                int j = 4*j4 + jj;
                float4 m4 = *(float4*)&Tb[j][4*ti];
                float mr[4] = {m4.x,m4.y,m4.z,m4.w};
                float4 v4 = *(float4*)&Vb[j][4*tv];
                float vt[4] = {v4.x,v4.y,v4.z,v4.w};
                #pragma unroll
                for (int r = 0; r < 4; ++r)
                    #pragma unroll
                    for (int s = 0; s < 4; ++s)
                        acc[r][s] += mr[r]*vt[s];
            }
        }
        __hip_bfloat16* Odst = Oin_all + obase;
        #pragma unroll
        for (int r = 0; r < 4; ++r)
            store_bf16x4(&Odst[(size_t)(4*ti+r)*64 + 4*tv], acc[r][0],acc[r][1],acc[r][2],acc[r][3]);
    }
}

// ---------------- Phase 2: sequential over chunks ----------------
// block = h*4 + vg (16 columns per block). waves: 0 = O-pass, 1 = S-pass, 2/3 = prefetch
__global__ __launch_bounds__(256) void phase2_kernel(
    const float* __restrict__ PT_all, const __hip_bfloat16* __restrict__ B_all,
    const float* __restrict__ RT_all, const __hip_bfloat16* __restrict__ Oin_all,
    float* __restrict__ y)
{
    const int h = blockIdx.x >> 2, vg = blockIdx.x & 3;
    const int tid = threadIdx.x;
    const int wave = tid >> 6, lane = tid & 63;

    __shared__ float PT_s[2][64][68];
    __shared__ float RT_s[2][64][68];
    __shared__ float B_s[2][64][20];
    __shared__ float O_s[2][64][20];
    __shared__ float S_s[2][64][20];

    for (int i = tid; i < 64*20; i += 256) ((float*)S_s[0])[i] = 0.f;

    const size_t hb = (size_t)h * NCHUNK;

    // prologue: stage chunk 0 into buffer 0 (all threads)
    {
        const float* Ps = PT_all + hb*4096;
        const float* Rs = RT_all + hb*4096;
        #pragma unroll
        for (int j = 0; j < 4; ++j) {
            int idx = tid + j*256;
            int row = idx >> 4, c4 = (idx & 15)*4;
            *(float4*)&PT_s[0][row][c4] = *(const float4*)&Ps[(size_t)row*64 + c4];
            *(float4*)&RT_s[0][row][c4] = *(const float4*)&Rs[(size_t)row*64 + c4];
        }
        if (tid < 128) {
            const __hip_bfloat16* Bs = B_all + hb*4096 + vg*16;
            const __hip_bfloat16* Os = Oin_all + hb*4096 + vg*16;
            int row = tid >> 1, c8 = (tid & 1)*8;
            unpack8(*(const uint4*)&Bs[(size_t)row*64 + c8], &B_s[0][row][c8]);
            unpack8(*(const uint4*)&Os[(size_t)row*64 + c8], &O_s[0][row][c8]);
        }
    }
    __syncthreads();

    for (int c = 0; c < NCHUNK; ++c) {
        const int cb = c & 1, nb = cb ^ 1;
        if (wave >= 2) {
            if (c + 1 < NCHUNK) {
                const int ll = (wave-2)*64 + lane;
                const float* Ps = PT_all + (hb + c+1)*4096;
                const float* Rs = RT_all + (hb + c+1)*4096;
                #pragma unroll
                for (int j = 0; j < 8; ++j) {
                    int idx = ll + j*128;
                    int row = idx >> 4, c4 = (idx & 15)*4;
                    *(float4*)&PT_s[nb][row][c4] = *(const float4*)&Ps[(size_t)row*64 + c4];
                    *(float4*)&RT_s[nb][row][c4] = *(const float4*)&Rs[(size_t)row*64 + c4];
                }
                const __hip_bfloat16* Bs = B_all + (hb + c+1)*4096 + vg*16;
                const __hip_bfloat16* Os = Oin_all + (hb + c+1)*4096 + vg*16;
                int row = ll >> 1, c8 = (ll & 1)*8;
                unpack8(*(const uint4*)&Bs[(size_t)row*64 + c8], &B_s[nb][row][c8]);
                unpack8(*(const uint4*)&Os[(size_t)row*64 + c8], &O_s[nb][row][c8]);
            }
        } else if (wave == 0) {
            // O = R*S + Oin
            int ti = lane >> 2, tv = lane & 3;
            float acc[4][4];
            #pragma unroll
            for (int r = 0; r < 4; ++r) {
                float4 o4 = *(float4*)&O_s[cb][4*ti+r][4*tv];
                acc[r][0]=o4.x; acc[r][1]=o4.y; acc[r][2]=o4.z; acc[r][3]=o4.w;
            }
            for (int k = 0; k < 64; ++k) {
                float4 r4 = *(float4*)&RT_s[cb][k][4*ti];
                float rr[4]={r4.x,r4.y,r4.z,r4.w};
                float4 s4 = *(float4*)&S_s[cb][k][4*tv];
                float sv[4]={s4.x,s4.y,s4.z,s4.w};
                #pragma unroll
                for (int r = 0; r < 4; ++r)
                    #pragma unroll
                    for (int s = 0; s < 4; ++s)
                        acc[r][s] += rr[r]*sv[s];
            }
            float* yr = y + (size_t)(c*64)*VAL_DIM + h*64 + vg*16;
            #pragma unroll
            for (int r = 0; r < 4; ++r)
                *(float4*)&yr[(size_t)(4*ti+r)*VAL_DIM + 4*tv] =
                    make_float4(acc[r][0],acc[r][1],acc[r][2],acc[r][3]);
        } else {
            // S' = P*S + B  (write into next buffer)
            int tk = lane >> 2, tv = lane & 3;
            float acc[4][4];
            #pragma unroll
            for (int r = 0; r < 4; ++r) {
                float4 b4 = *(float4*)&B_s[cb][4*tk+r][4*tv];
                acc[r][0]=b4.x; acc[r][1]=b4.y; acc[r][2]=b4.z; acc[r][3]=b4.w;
            }
            for (int k2 = 0; k2 < 64; ++k2) {
                float4 p4 = *(float4*)&PT_s[cb][k2][4*tk];
                float pp[4]={p4.x,p4.y,p4.z,p4.w};
                float4 s4 = *(float4*)&S_s[cb][k2][4*tv];
                float sv[4]={s4.x,s4.y,s4.z,s4.w};
                #pragma unroll
                for (int r = 0; r < 4; ++r)
                    #pragma unroll
                    for (int s = 0; s < 4; ++s)
                        acc[r][s] += pp[r]*sv[s];
            }
            #pragma unroll
            for (int r = 0; r < 4; ++r)
                *(float4*)&S_s[nb][4*tk+r][4*tv] =
                    make_float4(acc[r][0],acc[r][1],acc[r][2],acc[r][3]);
        }
        __syncthreads();
    }
}

// ---------------- RMSNorm(dv) * norm_weight * silu(z) ----------------
__global__ __launch_bounds__(256) void rmsnorm_gate_kernel(
    const float* __restrict__ y, const float* __restrict__ z,
    const float* __restrict__ nw, float* __restrict__ yn)
{
    int row = blockIdx.x * 4 + (threadIdx.x >> 6);
    int lane = threadIdx.x & 63;
    float v = y[(size_t)row*64 + lane];
    float ss = v*v;
    #pragma unroll
    for (int off = 1; off < 64; off <<= 1) ss += __shfl_xor(ss, off, 64);
    float rn = rsqrtf(ss * (1.f/64.f) + 1e-6f);
    float zz = z[(size_t)row*64 + lane];
    yn[(size_t)row*64 + lane] = nw[lane] * v * rn * (zz / (1.f + expf(-zz)));
}

extern "C" void kernel_launch(void* const* d_in, const int* in_sizes, int n_in,
                              void* d_out, int out_size, void* d_ws, size_t ws_size,
                              hipStream_t stream)
{
    const float* x      = (const float*)d_in[0];
    const float* W_qkv  = (const float*)d_in[1];
    const float* W_z    = (const float*)d_in[2];
    const float* W_b    = (const float*)d_in[3];
    const float* W_a    = (const float*)d_in[4];
    const float* W_out  = (const float*)d_in[5];
    const float* conv_w = (const float*)d_in[6];
    const float* dt_b   = (const float*)d_in[7];
    const float* A_log  = (const float*)d_in[8];
    const float* nw     = (const float*)d_in[9];
    float* out = (float*)d_out;

    float* ws = (float*)d_ws;
    const size_t M1 = 1u << 20;
    // region [0,4M): qkv_raw (until conv), then PT_all/B_all/Oin_all (phase1+)
    float* qkv_raw = ws;
    float* PT_all  = ws;                                   // 2M f32
    __hip_bfloat16* B_all   = (__hip_bfloat16*)(ws + 2*M1); // 2M bf16
    __hip_bfloat16* Oin_all = (__hip_bfloat16*)(ws + 3*M1); // 2M bf16
    // region [4M,8M): qkv_act (until phase1), then yn (4..6M), y (6..8M)
    float* qkv_act = ws + 4*M1;
    float* yn_buf  = ws + 4*M1;
    float* y_buf   = ws + 6*M1;
    float* z_buf   = ws + 8*M1;    // 2M
    float* RT_all  = ws + 10*M1;   // 2M f32
    float* beta    = ws + 12*M1;
    float* g_buf   = ws + 12*M1 + 32768;

    dim3 blk(256);
    // 1) qkv = x @ W_qkv^T
    gemm_nt_f32<128,128,16><<<dim3(CONV_DIM/128, T_LEN/128), blk, 0, stream>>>(
        T_LEN, CONV_DIM, DIM, x, W_qkv, qkv_raw);
    // 2) z = x @ W_z^T
    gemm_nt_f32<128,128,16><<<dim3(VAL_DIM/128, T_LEN/128), blk, 0, stream>>>(
        T_LEN, VAL_DIM, DIM, x, W_z, z_buf);
    // 3) beta, g
    betag_kernel<<<dim3(T_LEN), blk, 0, stream>>>(x, W_b, W_a, dt_b, A_log, beta, g_buf);
    // 4) causal depthwise conv + silu
    conv_silu_kernel<<<dim3(CONV_DIM/256, T_LEN), blk, 0, stream>>>(qkv_raw, conv_w, qkv_act);
    // 5) phase 1: WY factors -> P,B,R,Oin  (overwrites qkv_raw region)
    phase1_kernel<<<dim3(NV*NCHUNK), blk, 0, stream>>>(
        qkv_act, g_buf, beta, PT_all, B_all, RT_all, Oin_all);
    // 6) phase 2: sequential chunk recurrence
    phase2_kernel<<<dim3(NV*4), blk, 0, stream>>>(PT_all, B_all, RT_all, Oin_all, y_buf);
    // 7) RMSNorm + gate
    rmsnorm_gate_kernel<<<dim3(T_LEN*NV/4), blk, 0, stream>>>(y_buf, z_buf, nw, yn_buf);
    // 8) out = yn @ W_out^T
    gemm_nt_f32<128,128,16><<<dim3(DIM/128, T_LEN/128), blk, 0, stream>>>(
        T_LEN, DIM, VAL_DIM, yn_buf, W_out, out);
}

// Round 4
// 568.667 us; speedup vs baseline: 2.8173x; 1.8515x over previous
//
#include <hip/hip_runtime.h>
#include <hip/hip_bf16.h>
#include <math.h>

#define T_LEN 2048
#define DIM 2048
#define CONV_DIM 2048
#define KEY_DIM 512
#define VAL_DIM 1024
#define NK 8
#define NV 16
#define NCHUNK 32

typedef unsigned short ushort_t;
typedef __bf16 bf16x8 __attribute__((ext_vector_type(8)));
typedef float f32x4 __attribute__((ext_vector_type(4)));

// ---------------- helpers ----------------
static __device__ __forceinline__ void unpack8(uint4 raw, float* dst) {
    dst[0] = __uint_as_float(raw.x << 16);
    dst[1] = __uint_as_float(raw.x & 0xffff0000u);
    dst[2] = __uint_as_float(raw.y << 16);
    dst[3] = __uint_as_float(raw.y & 0xffff0000u);
    dst[4] = __uint_as_float(raw.z << 16);
    dst[5] = __uint_as_float(raw.z & 0xffff0000u);
    dst[6] = __uint_as_float(raw.w << 16);
    dst[7] = __uint_as_float(raw.w & 0xffff0000u);
}
static __device__ __forceinline__ unsigned short f2bf(float f) {
    unsigned int u = __float_as_uint(f);
    unsigned int r = (u + 0x7fffu + ((u >> 16) & 1u)) >> 16;
    return (unsigned short)r;
}
static __device__ __forceinline__ void store_bf16x4(ushort_t* dst, float a, float b, float c, float d) {
    union { unsigned short h[4]; uint2 u; } p;
    p.h[0] = f2bf(a); p.h[1] = f2bf(b); p.h[2] = f2bf(c); p.h[3] = f2bf(d);
    *(uint2*)dst = p.u;
}

#define GL2LDS(g, l) __builtin_amdgcn_global_load_lds( \
    (const __attribute__((address_space(1))) void*)(g), \
    (__attribute__((address_space(3))) void*)(l), 16, 0, 0)

// ---------------- f32 -> bf16 conversion (8 elems/thread) ----------------
__global__ __launch_bounds__(256) void f32_to_bf16_kernel(
    const float* __restrict__ in, ushort_t* __restrict__ out)
{
    size_t i = ((size_t)blockIdx.x * 256 + threadIdx.x) * 8;
    float4 v0 = *(const float4*)&in[i];
    float4 v1 = *(const float4*)&in[i + 4];
    union { unsigned short h[8]; uint4 u; } p;
    p.h[0]=f2bf(v0.x); p.h[1]=f2bf(v0.y); p.h[2]=f2bf(v0.z); p.h[3]=f2bf(v0.w);
    p.h[4]=f2bf(v1.x); p.h[5]=f2bf(v1.y); p.h[6]=f2bf(v1.z); p.h[7]=f2bf(v1.w);
    *(uint4*)&out[i] = p.u;
}

// ---------------- GEMM: C[M,N] = A[M,K] @ W[N,K]^T  (bf16 MFMA, m97 structure) ----------------
// 128x128 tile, BK=32, 4 waves, each wave 64x64 (4x4 fragments of 16x16x32).
__global__ __launch_bounds__(256) void gemm_bt_bf16(
    int M, int N, int K,
    const ushort_t* __restrict__ A,
    const ushort_t* __restrict__ W,
    float* __restrict__ C)
{
    __shared__ __align__(16) ushort_t As[128 * 32];
    __shared__ __align__(16) ushort_t Bs[128 * 32];
    const int tid = threadIdx.x;
    const int l = tid & 63;
    const int w = tid >> 6;
    const int wr = w >> 1, wc = w & 1;
    const int m0 = blockIdx.y * 128, n0 = blockIdx.x * 128;

    f32x4 acc[4][4];
    #pragma unroll
    for (int i = 0; i < 4; ++i)
        #pragma unroll
        for (int j = 0; j < 4; ++j)
            #pragma unroll
            for (int r = 0; r < 4; ++r) acc[i][j][r] = 0.f;

    // staging addresses: lane l covers row (l>>2), bytes (l&3)*16 within a 64-row half-tile
    const int srow = w * 16 + (l >> 2);
    const int scol = (l & 3) * 8;
    const ushort_t* gA0 = A + (size_t)(m0 + srow) * K + scol;
    const ushort_t* gA1 = A + (size_t)(m0 + 64 + srow) * K + scol;
    const ushort_t* gB0 = W + (size_t)(n0 + srow) * K + scol;
    const ushort_t* gB1 = W + (size_t)(n0 + 64 + srow) * K + scol;
    ushort_t* lA0 = &As[(w * 16) * 32];        // wave-uniform LDS base
    ushort_t* lA1 = &As[(64 + w * 16) * 32];
    ushort_t* lB0 = &Bs[(w * 16) * 32];
    ushort_t* lB1 = &Bs[(64 + w * 16) * 32];

    const int kq = (l >> 4) * 8;   // k-offset within fragment
    const int rr = l & 15;         // row/col within 16-tile

    for (int k0 = 0; k0 < K; k0 += 32) {
        __syncthreads();           // all waves done reading previous LDS tile
        GL2LDS(gA0 + k0, lA0);
        GL2LDS(gA1 + k0, lA1);
        GL2LDS(gB0 + k0, lB0);
        GL2LDS(gB1 + k0, lB1);
        __syncthreads();           // vmcnt drained by barrier semantics -> LDS ready
        bf16x8 af[4], bf[4];
        #pragma unroll
        for (int i = 0; i < 4; ++i) {
            af[i] = *(const bf16x8*)&As[(wr * 64 + i * 16 + rr) * 32 + kq];
            bf[i] = *(const bf16x8*)&Bs[(wc * 64 + i * 16 + rr) * 32 + kq];
        }
        #pragma unroll
        for (int i = 0; i < 4; ++i)
            #pragma unroll
            for (int j = 0; j < 4; ++j)
                acc[i][j] = __builtin_amdgcn_mfma_f32_16x16x32_bf16(af[i], bf[j], acc[i][j], 0, 0, 0);
    }

    // C/D layout: col = lane&15, row = (lane>>4)*4 + reg
    const int crow = (l >> 4) * 4, ccol = l & 15;
    #pragma unroll
    for (int i = 0; i < 4; ++i)
        #pragma unroll
        for (int j = 0; j < 4; ++j) {
            float* cp = &C[(size_t)(m0 + wr * 64 + i * 16 + crow) * N + n0 + wc * 64 + j * 16 + ccol];
            #pragma unroll
            for (int r = 0; r < 4; ++r) cp[(size_t)r * N] = acc[i][j][r];
        }
}

// ---------------- beta/g ----------------
__global__ __launch_bounds__(256) void betag_kernel(
    const float* __restrict__ x, const float* __restrict__ Wb, const float* __restrict__ Wa,
    const float* __restrict__ dt_bias, const float* __restrict__ A_log,
    float* __restrict__ beta, float* __restrict__ g)
{
    int t = blockIdx.x;
    __shared__ float xs[DIM];
    for (int i = threadIdx.x; i < DIM; i += 256) xs[i] = x[(size_t)t*DIM + i];
    __syncthreads();
    int wave = threadIdx.x >> 6, lane = threadIdx.x & 63;
    for (int o = wave; o < 2*NV; o += 4) {
        int n = o & (NV-1);
        const float* Wr = ((o < NV) ? Wb : Wa) + (size_t)n * DIM;
        float s = 0.f;
        for (int k = lane; k < DIM; k += 64) s += xs[k] * Wr[k];
        #pragma unroll
        for (int off = 1; off < 64; off <<= 1) s += __shfl_xor(s, off, 64);
        if (lane == 0) {
            if (o < NV) {
                beta[(size_t)t*NV + n] = 1.f / (1.f + expf(-s));
            } else {
                float sp = s + dt_bias[n];
                sp = (sp > 20.f) ? sp : log1pf(expf(sp));
                g[(size_t)t*NV + n] = -expf(A_log[n]) * sp;
            }
        }
    }
}

// ---------------- causal depthwise conv (K=4) + SiLU ----------------
__global__ __launch_bounds__(256) void conv_silu_kernel(
    const float* __restrict__ qkv_raw,
    const float* __restrict__ conv_w,
    float* __restrict__ qkv_act)
{
    int c = blockIdx.x * 256 + threadIdx.x;
    int t = blockIdx.y;
    float4 w = ((const float4*)conv_w)[c];
    float s = 0.f;
    if (t >= 3) s += qkv_raw[(size_t)(t-3)*CONV_DIM + c] * w.x;
    if (t >= 2) s += qkv_raw[(size_t)(t-2)*CONV_DIM + c] * w.y;
    if (t >= 1) s += qkv_raw[(size_t)(t-1)*CONV_DIM + c] * w.z;
    s += qkv_raw[(size_t)t*CONV_DIM + c] * w.w;
    qkv_act[(size_t)t*CONV_DIM + c] = s / (1.f + expf(-s));
}

// ---------------- Phase 1: per (head, chunk) WY factors -> P, B, R, Oin ----------------
__global__ __launch_bounds__(256) void phase1_kernel(
    const float* __restrict__ qkv_act,
    const float* __restrict__ g, const float* __restrict__ beta,
    float* __restrict__ PT_all, ushort_t* __restrict__ B_all,
    float* __restrict__ RT_all, ushort_t* __restrict__ Oin_all)
{
    const int hc = blockIdx.x;
    const int h = hc >> 5, c = hc & 31;
    const int hs = h >> 1;
    const int tid = threadIdx.x;
    const int t0 = c * 64;

    __shared__ float Kb[64][68];
    __shared__ float Vb[64][68];
    __shared__ float Qb[64][68];
    __shared__ float Ab[64][68];
    __shared__ float Tb[64][68];
    __shared__ float gam[64], w1[64], w2[64], sce[64], eg[64];
    __shared__ float eC_s;

    #pragma unroll
    for (int r = 0; r < 4; ++r) {
        int id = tid + r*256;
        int row = id >> 4;
        int dq = (id & 15) * 4;
        const float* src = &qkv_act[(size_t)(t0+row)*CONV_DIM];
        *(float4*)&Qb[row][dq] = *(const float4*)&src[hs*64 + dq];
        *(float4*)&Kb[row][dq] = *(const float4*)&src[KEY_DIM + hs*64 + dq];
        *(float4*)&Vb[row][dq] = *(const float4*)&src[2*KEY_DIM + h*64 + dq];
    }
    __syncthreads();

    {
        int row = tid >> 2, q4 = (tid & 3) * 16;
        float sq = 0.f, sk = 0.f;
        #pragma unroll
        for (int d = 0; d < 16; d += 4) {
            float4 qv = *(float4*)&Qb[row][q4+d];
            float4 kv = *(float4*)&Kb[row][q4+d];
            sq += qv.x*qv.x + qv.y*qv.y + qv.z*qv.z + qv.w*qv.w;
            sk += kv.x*kv.x + kv.y*kv.y + kv.z*kv.z + kv.w*kv.w;
        }
        sq += __shfl_xor(sq, 1, 64); sq += __shfl_xor(sq, 2, 64);
        sk += __shfl_xor(sk, 1, 64); sk += __shfl_xor(sk, 2, 64);
        float rq = rsqrtf(sq + 1e-6f) * 0.125f;
        float rk = rsqrtf(sk + 1e-6f);
        #pragma unroll
        for (int d = 0; d < 16; d += 4) {
            float4 qv = *(float4*)&Qb[row][q4+d];
            qv.x*=rq; qv.y*=rq; qv.z*=rq; qv.w*=rq;
            *(float4*)&Qb[row][q4+d] = qv;
            float4 kv = *(float4*)&Kb[row][q4+d];
            kv.x*=rk; kv.y*=rk; kv.z*=rk; kv.w*=rk;
            *(float4*)&Kb[row][q4+d] = kv;
        }
    }
    if (tid < 64) {
        float gv = g[(size_t)(t0+tid)*NV + h];
        float bv = beta[(size_t)(t0+tid)*NV + h];
        #pragma unroll
        for (int off = 1; off < 64; off <<= 1) {
            float n = __shfl_up(gv, off, 64);
            if (tid >= off) gv += n;
        }
        gam[tid] = gv;
        float e = expf(gv);
        eg[tid] = e;
        w1[tid] = bv * e;
        w2[tid] = bv;
        float gC = __shfl(gv, 63, 64);
        sce[tid] = expf(gC - gv);
        if (tid == 63) eC_s = e;
    }
    __syncthreads();

    {
        int ti = tid >> 4, tj = tid & 15;
        if (tj <= ti) {
            float acc[4][4] = {};
            for (int d4 = 0; d4 < 16; ++d4) {
                float ki[4][4], kj[4][4];
                #pragma unroll
                for (int r = 0; r < 4; ++r) {
                    float4 a = *(float4*)&Kb[4*ti+r][4*d4];
                    ki[r][0]=a.x; ki[r][1]=a.y; ki[r][2]=a.z; ki[r][3]=a.w;
                    float4 b = *(float4*)&Kb[4*tj+r][4*d4];
                    kj[r][0]=b.x; kj[r][1]=b.y; kj[r][2]=b.z; kj[r][3]=b.w;
                }
                #pragma unroll
                for (int r = 0; r < 4; ++r)
                    #pragma unroll
                    for (int s = 0; s < 4; ++s)
                        #pragma unroll
                        for (int d = 0; d < 4; ++d)
                            acc[r][s] += ki[r][d]*kj[s][d];
            }
            #pragma unroll
            for (int r = 0; r < 4; ++r) {
                int ii = 4*ti + r;
                float o[4];
                #pragma unroll
                for (int s = 0; s < 4; ++s) {
                    int jj = 4*tj + s;
                    o[s] = (jj < ii) ? acc[r][s]*w2[ii]*expf(gam[ii]-gam[jj]) : 0.f;
                }
                *(float4*)&Ab[ii][4*tj] = make_float4(o[0],o[1],o[2],o[3]);
            }
        }
    }
    #pragma unroll
    for (int r = 0; r < 4; ++r) {
        int id = tid + r*256;
        int row = id >> 4, dq = (id & 15)*4;
        *(float4*)&Tb[row][dq] = make_float4(row==dq?1.f:0.f, row==dq+1?1.f:0.f,
                                             row==dq+2?1.f:0.f, row==dq+3?1.f:0.f);
    }
    __syncthreads();
    if (tid < 64) {
        int col = tid;
        for (int i = 1; i < 64; ++i) {
            float acc = 0.f;
            int nj4 = (i + 3) >> 2;
            for (int j4 = 0; j4 < nj4; ++j4) {
                float4 a = *(float4*)&Ab[i][4*j4];
                int j = 4*j4;
                acc += a.x * Tb[j  ][col];
                acc += a.y * Tb[j+1][col];
                acc += a.z * Tb[j+2][col];
                acc += a.w * Tb[j+3][col];
            }
            Tb[i][col] = ((i==col)?1.f:0.f) - acc;
        }
    }
    __syncthreads();

    {
        int ti = tid >> 4, td = tid & 15;
        float acc[4][4] = {};
        for (int j4 = 0; j4 <= ti; ++j4) {
            float tr[4][4];
            #pragma unroll
            for (int r = 0; r < 4; ++r) {
                float4 a = *(float4*)&Tb[4*ti+r][4*j4];
                tr[r][0]=a.x; tr[r][1]=a.y; tr[r][2]=a.z; tr[r][3]=a.w;
            }
            float4 wv4 = *(float4*)&w1[4*j4];
            float wv[4] = {wv4.x, wv4.y, wv4.z, wv4.w};
            #pragma unroll
            for (int s = 0; s < 4; ++s) {
                float4 kr = *(float4*)&Kb[4*j4+s][4*td];
                #pragma unroll
                for (int r = 0; r < 4; ++r) {
                    float tw = tr[r][s]*wv[s];
                    acc[r][0] += tw*kr.x; acc[r][1] += tw*kr.y;
                    acc[r][2] += tw*kr.z; acc[r][3] += tw*kr.w;
                }
            }
        }
        #pragma unroll
        for (int r = 0; r < 4; ++r)
            *(float4*)&Ab[4*ti+r][4*td] = make_float4(acc[r][0],acc[r][1],acc[r][2],acc[r][3]);
    }
    __syncthreads();

    {
        int il = tid >> 4, td = tid & 15;
        for (int blk = 3; blk >= 0; --blk) {
            int i = blk*16 + il;
            float a0=0.f,a1=0.f,a2=0.f,a3=0.f;
            int nj4 = i >> 2;
            for (int j4 = 0; j4 <= nj4; ++j4) {
                float4 tr4 = *(float4*)&Tb[i][4*j4];
                float tr[4] = {tr4.x,tr4.y,tr4.z,tr4.w};
                float4 wv4 = *(float4*)&w2[4*j4];
                float wv[4] = {wv4.x,wv4.y,wv4.z,wv4.w};
                #pragma unroll
                for (int s = 0; s < 4; ++s) {
                    float tw = tr[s]*wv[s];
                    float4 vr = *(float4*)&Vb[4*j4+s][4*td];
                    a0 += tw*vr.x; a1 += tw*vr.y; a2 += tw*vr.z; a3 += tw*vr.w;
                }
            }
            __syncthreads();
            *(float4*)&Vb[i][4*td] = make_float4(a0,a1,a2,a3);
            __syncthreads();
        }
    }

    {
        int tj = tid >> 4, ti_ = tid & 15;
        if (ti_ >= tj) {
            float acc[4][4] = {};
            for (int d4 = 0; d4 < 16; ++d4) {
                float kj[4][4], qi[4][4];
                #pragma unroll
                for (int r = 0; r < 4; ++r) {
                    float4 a = *(float4*)&Kb[4*tj+r][4*d4];
                    kj[r][0]=a.x; kj[r][1]=a.y; kj[r][2]=a.z; kj[r][3]=a.w;
                    float4 b = *(float4*)&Qb[4*ti_+r][4*d4];
                    qi[r][0]=b.x; qi[r][1]=b.y; qi[r][2]=b.z; qi[r][3]=b.w;
                }
                #pragma unroll
                for (int r = 0; r < 4; ++r)
                    #pragma unroll
                    for (int s = 0; s < 4; ++s)
                        #pragma unroll
                        for (int d = 0; d < 4; ++d)
                            acc[r][s] += kj[r][d]*qi[s][d];
            }
            #pragma unroll
            for (int r = 0; r < 4; ++r) {
                int jj = 4*tj + r;
                float o[4];
                #pragma unroll
                for (int s = 0; s < 4; ++s) {
                    int ii = 4*ti_ + s;
                    o[s] = (ii >= jj) ? acc[r][s]*expf(gam[ii]-gam[jj]) : 0.f;
                }
                *(float4*)&Tb[jj][4*ti_] = make_float4(o[0],o[1],o[2],o[3]);
            }
        }
    }
    __syncthreads();

    const size_t obase = (size_t)(h*NCHUNK + c) * 4096;

    {
        int t2 = tid >> 4, t1 = tid & 15;
        float acc[4][4] = {};
        for (int i = 0; i < 64; ++i) {
            float sc = sce[i];
            float4 k4 = *(float4*)&Kb[i][4*t1];
            float ks[4] = {k4.x*sc, k4.y*sc, k4.z*sc, k4.w*sc};
            float4 w4 = *(float4*)&Ab[i][4*t2];
            float wr[4] = {w4.x,w4.y,w4.z,w4.w};
            #pragma unroll
            for (int r = 0; r < 4; ++r)
                #pragma unroll
                for (int s = 0; s < 4; ++s)
                    acc[r][s] += ks[r]*wr[s];
        }
        float eC = eC_s;
        float* Pdst = PT_all + obase;
        #pragma unroll
        for (int s = 0; s < 4; ++s) {
            int d2 = 4*t2 + s;
            float o[4];
            #pragma unroll
            for (int r = 0; r < 4; ++r) {
                int d1 = 4*t1 + r;
                o[r] = ((d1==d2) ? eC : 0.f) - acc[r][s];
            }
            *(float4*)&Pdst[(size_t)d2*64 + 4*t1] = make_float4(o[0],o[1],o[2],o[3]);
        }
    }
    {
        int td = tid >> 4, tv = tid & 15;
        float acc[4][4] = {};
        for (int i = 0; i < 64; ++i) {
            float sc = sce[i];
            float4 k4 = *(float4*)&Kb[i][4*td];
            float ks[4] = {k4.x*sc, k4.y*sc, k4.z*sc, k4.w*sc};
            float4 v4 = *(float4*)&Vb[i][4*tv];
            float vt[4] = {v4.x,v4.y,v4.z,v4.w};
            #pragma unroll
            for (int r = 0; r < 4; ++r)
                #pragma unroll
                for (int s = 0; s < 4; ++s)
                    acc[r][s] += ks[r]*vt[s];
        }
        ushort_t* Bdst = B_all + obase;
        #pragma unroll
        for (int r = 0; r < 4; ++r)
            store_bf16x4(&Bdst[(size_t)(4*td+r)*64 + 4*tv], acc[r][0],acc[r][1],acc[r][2],acc[r][3]);
    }
    {
        int td = tid >> 4, ti = tid & 15;
        float acc[4][4] = {};
        for (int j4 = 0; j4 <= ti; ++j4) {
            #pragma unroll
            for (int jj = 0; jj < 4; ++jj) {
                int j = 4*j4 + jj;
                float4 m4 = *(float4*)&Tb[j][4*ti];
                float mr[4] = {m4.x,m4.y,m4.z,m4.w};
                float4 w4 = *(float4*)&Ab[j][4*td];
                float wr[4] = {w4.x,w4.y,w4.z,w4.w};
                #pragma unroll
                for (int r = 0; r < 4; ++r)
                    #pragma unroll
                    for (int s = 0; s < 4; ++s)
                        acc[r][s] += mr[r]*wr[s];
            }
        }
        float val[4][4];
        #pragma unroll
        for (int r = 0; r < 4; ++r) {
            int i = 4*ti + r;
            float e = eg[i];
            float4 q4 = *(float4*)&Qb[i][4*td];
            val[r][0] = e*q4.x - acc[r][0];
            val[r][1] = e*q4.y - acc[r][1];
            val[r][2] = e*q4.z - acc[r][2];
            val[r][3] = e*q4.w - acc[r][3];
        }
        float* Rdst = RT_all + obase;
        #pragma unroll
        for (int s = 0; s < 4; ++s)
            *(float4*)&Rdst[(size_t)(4*td+s)*64 + 4*ti] = make_float4(val[0][s],val[1][s],val[2][s],val[3][s]);
    }
    {
        int ti = tid >> 4, tv = tid & 15;
        float acc[4][4] = {};
        for (int j4 = 0; j4 <= ti; ++j4) {
            #pragma unroll
            for (int jj = 0; jj < 4; ++jj) {
                int j = 4*j4 + jj;
                float4 m4 = *(float4*)&Tb[j][4*ti];
                float mr[4] = {m4.x,m4.y,m4.z,m4.w};
                float4 v4 = *(float4*)&Vb[j][4*tv];
                float vt[4] = {v4.x,v4.y,v4.z,v4.w};
                #pragma unroll
                for (int r = 0; r < 4; ++r)
                    #pragma unroll
                    for (int s = 0; s < 4; ++s)
                        acc[r][s] += mr[r]*vt[s];
            }
        }
        ushort_t* Odst = Oin_all + obase;
        #pragma unroll
        for (int r = 0; r < 4; ++r)
            store_bf16x4(&Odst[(size_t)(4*ti+r)*64 + 4*tv], acc[r][0],acc[r][1],acc[r][2],acc[r][3]);
    }
}

// ---------------- Phase 2: sequential over chunks ----------------
__global__ __launch_bounds__(256) void phase2_kernel(
    const float* __restrict__ PT_all, const ushort_t* __restrict__ B_all,
    const float* __restrict__ RT_all, const ushort_t* __restrict__ Oin_all,
    float* __restrict__ y)
{
    const int h = blockIdx.x >> 2, vg = blockIdx.x & 3;
    const int tid = threadIdx.x;
    const int wave = tid >> 6, lane = tid & 63;

    __shared__ float PT_s[2][64][68];
    __shared__ float RT_s[2][64][68];
    __shared__ float B_s[2][64][20];
    __shared__ float O_s[2][64][20];
    __shared__ float S_s[2][64][20];

    for (int i = tid; i < 64*20; i += 256) ((float*)S_s[0])[i] = 0.f;

    const size_t hb = (size_t)h * NCHUNK;

    {
        const float* Ps = PT_all + hb*4096;
        const float* Rs = RT_all + hb*4096;
        #pragma unroll
        for (int j = 0; j < 4; ++j) {
            int idx = tid + j*256;
            int row = idx >> 4, c4 = (idx & 15)*4;
            *(float4*)&PT_s[0][row][c4] = *(const float4*)&Ps[(size_t)row*64 + c4];
            *(float4*)&RT_s[0][row][c4] = *(const float4*)&Rs[(size_t)row*64 + c4];
        }
        if (tid < 128) {
            const ushort_t* Bs = B_all + hb*4096 + vg*16;
            const ushort_t* Os = Oin_all + hb*4096 + vg*16;
            int row = tid >> 1, c8 = (tid & 1)*8;
            unpack8(*(const uint4*)&Bs[(size_t)row*64 + c8], &B_s[0][row][c8]);
            unpack8(*(const uint4*)&Os[(size_t)row*64 + c8], &O_s[0][row][c8]);
        }
    }
    __syncthreads();

    for (int c = 0; c < NCHUNK; ++c) {
        const int cb = c & 1, nb = cb ^ 1;
        if (wave >= 2) {
            if (c + 1 < NCHUNK) {
                const int ll = (wave-2)*64 + lane;
                const float* Ps = PT_all + (hb + c+1)*4096;
                const float* Rs = RT_all + (hb + c+1)*4096;
                #pragma unroll
                for (int j = 0; j < 8; ++j) {
                    int idx = ll + j*128;
                    int row = idx >> 4, c4 = (idx & 15)*4;
                    *(float4*)&PT_s[nb][row][c4] = *(const float4*)&Ps[(size_t)row*64 + c4];
                    *(float4*)&RT_s[nb][row][c4] = *(const float4*)&Rs[(size_t)row*64 + c4];
                }
                const ushort_t* Bs = B_all + (hb + c+1)*4096 + vg*16;
                const ushort_t* Os = Oin_all + (hb + c+1)*4096 + vg*16;
                int row = ll >> 1, c8 = (ll & 1)*8;
                unpack8(*(const uint4*)&Bs[(size_t)row*64 + c8], &B_s[nb][row][c8]);
                unpack8(*(const uint4*)&Os[(size_t)row*64 + c8], &O_s[nb][row][c8]);
            }
        } else if (wave == 0) {
            int ti = lane >> 2, tv = lane & 3;
            float acc[4][4];
            #pragma unroll
            for (int r = 0; r < 4; ++r) {
                float4 o4 = *(float4*)&O_s[cb][4*ti+r][4*tv];
                acc[r][0]=o4.x; acc[r][1]=o4.y; acc[r][2]=o4.z; acc[r][3]=o4.w;
            }
            for (int k = 0; k < 64; ++k) {
                float4 r4 = *(float4*)&RT_s[cb][k][4*ti];
                float rr[4]={r4.x,r4.y,r4.z,r4.w};
                float4 s4 = *(float4*)&S_s[cb][k][4*tv];
                float sv[4]={s4.x,s4.y,s4.z,s4.w};
                #pragma unroll
                for (int r = 0; r < 4; ++r)
                    #pragma unroll
                    for (int s = 0; s < 4; ++s)
                        acc[r][s] += rr[r]*sv[s];
            }
            float* yr = y + (size_t)(c*64)*VAL_DIM + h*64 + vg*16;
            #pragma unroll
            for (int r = 0; r < 4; ++r)
                *(float4*)&yr[(size_t)(4*ti+r)*VAL_DIM + 4*tv] =
                    make_float4(acc[r][0],acc[r][1],acc[r][2],acc[r][3]);
        } else if (wave == 1) {
            int tk = lane >> 2, tv = lane & 3;
            float acc[4][4];
            #pragma unroll
            for (int r = 0; r < 4; ++r) {
                float4 b4 = *(float4*)&B_s[cb][4*tk+r][4*tv];
                acc[r][0]=b4.x; acc[r][1]=b4.y; acc[r][2]=b4.z; acc[r][3]=b4.w;
            }
            for (int k2 = 0; k2 < 64; ++k2) {
                float4 p4 = *(float4*)&PT_s[cb][k2][4*tk];
                float pp[4]={p4.x,p4.y,p4.z,p4.w};
                float4 s4 = *(float4*)&S_s[cb][k2][4*tv];
                float sv[4]={s4.x,s4.y,s4.z,s4.w};
                #pragma unroll
                for (int r = 0; r < 4; ++r)
                    #pragma unroll
                    for (int s = 0; s < 4; ++s)
                        acc[r][s] += pp[r]*sv[s];
            }
            #pragma unroll
            for (int r = 0; r < 4; ++r)
                *(float4*)&S_s[nb][4*tk+r][4*tv] =
                    make_float4(acc[r][0],acc[r][1],acc[r][2],acc[r][3]);
        }
        __syncthreads();
    }
}

// ---------------- RMSNorm(dv) * norm_weight * silu(z)  -> bf16 ----------------
__global__ __launch_bounds__(256) void rmsnorm_gate_kernel(
    const float* __restrict__ y, const float* __restrict__ z,
    const float* __restrict__ nw, ushort_t* __restrict__ yn)
{
    int row = blockIdx.x * 4 + (threadIdx.x >> 6);
    int lane = threadIdx.x & 63;
    float v = y[(size_t)row*64 + lane];
    float ss = v*v;
    #pragma unroll
    for (int off = 1; off < 64; off <<= 1) ss += __shfl_xor(ss, off, 64);
    float rn = rsqrtf(ss * (1.f/64.f) + 1e-6f);
    float zz = z[(size_t)row*64 + lane];
    yn[(size_t)row*64 + lane] = f2bf(nw[lane] * v * rn * (zz / (1.f + expf(-zz))));
}

extern "C" void kernel_launch(void* const* d_in, const int* in_sizes, int n_in,
                              void* d_out, int out_size, void* d_ws, size_t ws_size,
                              hipStream_t stream)
{
    const float* x      = (const float*)d_in[0];
    const float* W_qkv  = (const float*)d_in[1];
    const float* W_z    = (const float*)d_in[2];
    const float* W_b    = (const float*)d_in[3];
    const float* W_a    = (const float*)d_in[4];
    const float* W_out  = (const float*)d_in[5];
    const float* conv_w = (const float*)d_in[6];
    const float* dt_b   = (const float*)d_in[7];
    const float* A_log  = (const float*)d_in[8];
    const float* nw     = (const float*)d_in[9];
    float* out = (float*)d_out;

    float* ws = (float*)d_ws;
    const size_t M1 = 1u << 20;
    // [0,4M): qkv_raw (GEMM1 out) -> after phase1: PT(0..2M) B(2..3M) Oin(3..4M)
    float* qkv_raw   = ws;
    float* PT_all    = ws;
    ushort_t* B_all   = (ushort_t*)(ws + 2*M1);
    ushort_t* Oin_all = (ushort_t*)(ws + 3*M1);
    // [4M,8M): qkv_act (until phase1) -> yn_bf [4M,5M), Wout_bf [5M,6M), y [6M,8M)
    float* qkv_act   = ws + 4*M1;
    ushort_t* yn_bf   = (ushort_t*)(ws + 4*M1);
    ushort_t* Wout_bf = (ushort_t*)(ws + 5*M1);
    float* y_buf     = ws + 6*M1;
    ushort_t* x_bf    = (ushort_t*)(ws + 6*M1);   // dead before conv_silu/y
    // [8M,10M): Wqkv_bf (GEMM1 only) -> z_buf (GEMM2 out)
    ushort_t* Wqkv_bf = (ushort_t*)(ws + 8*M1);
    float* z_buf     = ws + 8*M1;
    // [10M,12M): Wz_bf [10M,11M) (until GEMM2) -> RT_all (phase1 out)
    ushort_t* Wz_bf   = (ushort_t*)(ws + 10*M1);
    float* RT_all    = ws + 10*M1;
    float* beta      = ws + 12*M1;
    float* g_buf     = ws + 12*M1 + 32768;

    dim3 blk(256);
    // 0) convert inputs to bf16
    f32_to_bf16_kernel<<<dim3(2048), blk, 0, stream>>>(x, x_bf);          // 4M
    f32_to_bf16_kernel<<<dim3(2048), blk, 0, stream>>>(W_qkv, Wqkv_bf);   // 4M
    f32_to_bf16_kernel<<<dim3(1024), blk, 0, stream>>>(W_z, Wz_bf);       // 2M
    // 1) qkv = x @ W_qkv^T   (bf16 MFMA)
    gemm_bt_bf16<<<dim3(CONV_DIM/128, T_LEN/128), blk, 0, stream>>>(
        T_LEN, CONV_DIM, DIM, x_bf, Wqkv_bf, qkv_raw);
    // 2) z = x @ W_z^T       (bf16 MFMA; overwrites Wqkv_bf region)
    gemm_bt_bf16<<<dim3(VAL_DIM/128, T_LEN/128), blk, 0, stream>>>(
        T_LEN, VAL_DIM, DIM, x_bf, Wz_bf, z_buf);
    // 3) beta, g
    betag_kernel<<<dim3(T_LEN), blk, 0, stream>>>(x, W_b, W_a, dt_b, A_log, beta, g_buf);
    // 4) causal depthwise conv + silu
    conv_silu_kernel<<<dim3(CONV_DIM/256, T_LEN), blk, 0, stream>>>(qkv_raw, conv_w, qkv_act);
    // 5) phase 1: WY factors
    phase1_kernel<<<dim3(NV*NCHUNK), blk, 0, stream>>>(
        qkv_act, g_buf, beta, PT_all, B_all, RT_all, Oin_all);
    // 6) phase 2: sequential chunk recurrence
    phase2_kernel<<<dim3(NV*4), blk, 0, stream>>>(PT_all, B_all, RT_all, Oin_all, y_buf);
    // 7) RMSNorm + gate -> bf16
    rmsnorm_gate_kernel<<<dim3(T_LEN*NV/4), blk, 0, stream>>>(y_buf, z_buf, nw, yn_bf);
    // 7b) convert W_out (region free only after phase1)
    f32_to_bf16_kernel<<<dim3(1024), blk, 0, stream>>>(W_out, Wout_bf);   // 2M
    // 8) out = yn @ W_out^T  (bf16 MFMA)
    gemm_bt_bf16<<<dim3(DIM/128, T_LEN/128), blk, 0, stream>>>(
        T_LEN, DIM, VAL_DIM, yn_bf, Wout_bf, out);
}

// Round 6
// 495.656 us; speedup vs baseline: 3.2323x; 1.1473x over previous
//
#include <hip/hip_runtime.h>
#include <hip/hip_bf16.h>
#include <math.h>

#define T_LEN 2048
#define DIM 2048
#define CONV_DIM 2048
#define KEY_DIM 512
#define VAL_DIM 1024
#define NK 8
#define NV 16
#define NCHUNK 32

typedef unsigned short ushort_t;
typedef __bf16 bf16x8 __attribute__((ext_vector_type(8)));
typedef float f32x4 __attribute__((ext_vector_type(4)));

// ---------------- helpers ----------------
static __device__ __forceinline__ void unpack8(uint4 raw, float* dst) {
    dst[0] = __uint_as_float(raw.x << 16);
    dst[1] = __uint_as_float(raw.x & 0xffff0000u);
    dst[2] = __uint_as_float(raw.y << 16);
    dst[3] = __uint_as_float(raw.y & 0xffff0000u);
    dst[4] = __uint_as_float(raw.z << 16);
    dst[5] = __uint_as_float(raw.z & 0xffff0000u);
    dst[6] = __uint_as_float(raw.w << 16);
    dst[7] = __uint_as_float(raw.w & 0xffff0000u);
}
static __device__ __forceinline__ unsigned short f2bf(float f) {
    unsigned int u = __float_as_uint(f);
    unsigned int r = (u + 0x7fffu + ((u >> 16) & 1u)) >> 16;
    return (unsigned short)r;
}
static __device__ __forceinline__ void store_bf16x4(ushort_t* dst, float a, float b, float c, float d) {
    union { unsigned short h[4]; uint2 u; } p;
    p.h[0] = f2bf(a); p.h[1] = f2bf(b); p.h[2] = f2bf(c); p.h[3] = f2bf(d);
    *(uint2*)dst = p.u;
}

#define GL2LDS(g, l) __builtin_amdgcn_global_load_lds( \
    (const __attribute__((address_space(1))) void*)(g), \
    (__attribute__((address_space(3))) void*)(l), 16, 0, 0)

// 64x64x64 X*Y^T on MFMA: X,Y bf16 LDS [64][72] row-major (X: [row][k], Y: [col][k]).
// Wave (wr,wc) computes its 32x32 quadrant into acc[2][2] fragments.
// Output element (fi,fj,r): row = wr*32+fi*16+(l>>4)*4+r, col = wc*32+fj*16+(l&15).
static __device__ __forceinline__ void mm64(
    const ushort_t* X, const ushort_t* Y, int wr, int wc, int l, f32x4 acc[2][2])
{
    const int rr = l & 15, kq = (l >> 4) * 8;
    #pragma unroll
    for (int i = 0; i < 2; ++i)
        #pragma unroll
        for (int j = 0; j < 2; ++j)
            #pragma unroll
            for (int r = 0; r < 4; ++r) acc[i][j][r] = 0.f;
    #pragma unroll
    for (int t = 0; t < 2; ++t) {
        bf16x8 a[2], b[2];
        #pragma unroll
        for (int i = 0; i < 2; ++i)
            a[i] = *(const bf16x8*)&X[(wr*32 + i*16 + rr)*72 + t*32 + kq];
        #pragma unroll
        for (int j = 0; j < 2; ++j)
            b[j] = *(const bf16x8*)&Y[(wc*32 + j*16 + rr)*72 + t*32 + kq];
        #pragma unroll
        for (int i = 0; i < 2; ++i)
            #pragma unroll
            for (int j = 0; j < 2; ++j)
                acc[i][j] = __builtin_amdgcn_mfma_f32_16x16x32_bf16(a[i], b[j], acc[i][j], 0, 0, 0);
    }
}

// ---------------- f32 -> bf16 conversion (8 elems/thread) ----------------
__global__ __launch_bounds__(256) void f32_to_bf16_kernel(
    const float* __restrict__ in, ushort_t* __restrict__ out)
{
    size_t i = ((size_t)blockIdx.x * 256 + threadIdx.x) * 8;
    float4 v0 = *(const float4*)&in[i];
    float4 v1 = *(const float4*)&in[i + 4];
    union { unsigned short h[8]; uint4 u; } p;
    p.h[0]=f2bf(v0.x); p.h[1]=f2bf(v0.y); p.h[2]=f2bf(v0.z); p.h[3]=f2bf(v0.w);
    p.h[4]=f2bf(v1.x); p.h[5]=f2bf(v1.y); p.h[6]=f2bf(v1.z); p.h[7]=f2bf(v1.w);
    *(uint4*)&out[i] = p.u;
}

// ---------------- GEMM: C[M,N] = A[M,K] @ W[N,K]^T  (bf16 MFMA, m97 structure) ----------------
__global__ __launch_bounds__(256) void gemm_bt_bf16(
    int M, int N, int K,
    const ushort_t* __restrict__ A,
    const ushort_t* __restrict__ W,
    float* __restrict__ C)
{
    __shared__ __align__(16) ushort_t As[128 * 32];
    __shared__ __align__(16) ushort_t Bs[128 * 32];
    const int tid = threadIdx.x;
    const int l = tid & 63;
    const int w = tid >> 6;
    const int wr = w >> 1, wc = w & 1;
    const int m0 = blockIdx.y * 128, n0 = blockIdx.x * 128;

    f32x4 acc[4][4];
    #pragma unroll
    for (int i = 0; i < 4; ++i)
        #pragma unroll
        for (int j = 0; j < 4; ++j)
            #pragma unroll
            for (int r = 0; r < 4; ++r) acc[i][j][r] = 0.f;

    const int srow = w * 16 + (l >> 2);
    const int scol = (l & 3) * 8;
    const ushort_t* gA0 = A + (size_t)(m0 + srow) * K + scol;
    const ushort_t* gA1 = A + (size_t)(m0 + 64 + srow) * K + scol;
    const ushort_t* gB0 = W + (size_t)(n0 + srow) * K + scol;
    const ushort_t* gB1 = W + (size_t)(n0 + 64 + srow) * K + scol;
    ushort_t* lA0 = &As[(w * 16) * 32];
    ushort_t* lA1 = &As[(64 + w * 16) * 32];
    ushort_t* lB0 = &Bs[(w * 16) * 32];
    ushort_t* lB1 = &Bs[(64 + w * 16) * 32];

    const int kq = (l >> 4) * 8;
    const int rr = l & 15;

    for (int k0 = 0; k0 < K; k0 += 32) {
        __syncthreads();
        GL2LDS(gA0 + k0, lA0);
        GL2LDS(gA1 + k0, lA1);
        GL2LDS(gB0 + k0, lB0);
        GL2LDS(gB1 + k0, lB1);
        __syncthreads();
        bf16x8 af[4], bf[4];
        #pragma unroll
        for (int i = 0; i < 4; ++i) {
            af[i] = *(const bf16x8*)&As[(wr * 64 + i * 16 + rr) * 32 + kq];
            bf[i] = *(const bf16x8*)&Bs[(wc * 64 + i * 16 + rr) * 32 + kq];
        }
        #pragma unroll
        for (int i = 0; i < 4; ++i)
            #pragma unroll
            for (int j = 0; j < 4; ++j)
                acc[i][j] = __builtin_amdgcn_mfma_f32_16x16x32_bf16(af[i], bf[j], acc[i][j], 0, 0, 0);
    }

    const int crow = (l >> 4) * 4, ccol = l & 15;
    #pragma unroll
    for (int i = 0; i < 4; ++i)
        #pragma unroll
        for (int j = 0; j < 4; ++j) {
            float* cp = &C[(size_t)(m0 + wr * 64 + i * 16 + crow) * N + n0 + wc * 64 + j * 16 + ccol];
            #pragma unroll
            for (int r = 0; r < 4; ++r) cp[(size_t)r * N] = acc[i][j][r];
        }
}

// ---------------- beta/g ----------------
__global__ __launch_bounds__(256) void betag_kernel(
    const float* __restrict__ x, const float* __restrict__ Wb, const float* __restrict__ Wa,
    const float* __restrict__ dt_bias, const float* __restrict__ A_log,
    float* __restrict__ beta, float* __restrict__ g)
{
    int t = blockIdx.x;
    __shared__ float xs[DIM];
    for (int i = threadIdx.x; i < DIM; i += 256) xs[i] = x[(size_t)t*DIM + i];
    __syncthreads();
    int wave = threadIdx.x >> 6, lane = threadIdx.x & 63;
    for (int o = wave; o < 2*NV; o += 4) {
        int n = o & (NV-1);
        const float* Wr = ((o < NV) ? Wb : Wa) + (size_t)n * DIM;
        float s = 0.f;
        for (int k = lane; k < DIM; k += 64) s += xs[k] * Wr[k];
        #pragma unroll
        for (int off = 1; off < 64; off <<= 1) s += __shfl_xor(s, off, 64);
        if (lane == 0) {
            if (o < NV) {
                beta[(size_t)t*NV + n] = 1.f / (1.f + expf(-s));
            } else {
                float sp = s + dt_bias[n];
                sp = (sp > 20.f) ? sp : log1pf(expf(sp));
                g[(size_t)t*NV + n] = -expf(A_log[n]) * sp;
            }
        }
    }
}

// ---------------- causal depthwise conv (K=4) + SiLU ----------------
__global__ __launch_bounds__(256) void conv_silu_kernel(
    const float* __restrict__ qkv_raw,
    const float* __restrict__ conv_w,
    float* __restrict__ qkv_act)
{
    int c = blockIdx.x * 256 + threadIdx.x;
    int t = blockIdx.y;
    float4 w = ((const float4*)conv_w)[c];
    float s = 0.f;
    if (t >= 3) s += qkv_raw[(size_t)(t-3)*CONV_DIM + c] * w.x;
    if (t >= 2) s += qkv_raw[(size_t)(t-2)*CONV_DIM + c] * w.y;
    if (t >= 1) s += qkv_raw[(size_t)(t-1)*CONV_DIM + c] * w.z;
    s += qkv_raw[(size_t)t*CONV_DIM + c] * w.w;
    qkv_act[(size_t)t*CONV_DIM + c] = s / (1.f + expf(-s));
}

// ---------------- Phase 1 (MFMA): per (head, chunk) WY factors -> P, B, R, Oin ----------------
__global__ __launch_bounds__(256) void phase1_kernel(
    const float* __restrict__ qkv_act,
    const float* __restrict__ g, const float* __restrict__ beta,
    float* __restrict__ PT_all, ushort_t* __restrict__ B_all,
    float* __restrict__ RT_all, ushort_t* __restrict__ Oin_all)
{
    const int hc = blockIdx.x;
    const int h = hc >> 5, c = hc & 31;
    const int hs = h >> 1;
    const int tid = threadIdx.x;
    const int l = tid & 63, w = tid >> 6;
    const int wr = w >> 1, wc = w & 1;
    const int t0 = c * 64;

    __shared__ float Qf[64][68];                       // persists (R epilogue)
    __shared__ __align__(16) float R1f[64*68];         // Kf -> Ab
    __shared__ __align__(16) float R2f[64*68];         // Vf -> Tb -> M16
    __shared__ __align__(16) ushort_t P4[5*64*72];     // Kb16,KT16,KTs16,Qb16,VT16
    __shared__ __align__(16) ushort_t R5[2*64*72];     // Tw1,Tw2 -> WT16,VtT16
    __shared__ float gam[64], w1s[64], w2s[64], sces[64], egs[64];
    __shared__ float eCs;

    float (*Kf)[68] = (float(*)[68])R1f;
    float (*Ab)[68] = (float(*)[68])R1f;
    float (*Vf)[68] = (float(*)[68])R2f;
    float (*Tb)[68] = (float(*)[68])R2f;
    ushort_t* M16   = (ushort_t*)R2f;        // [64][72] bf16
    ushort_t* Kb16  = P4;                    // K[t][d]
    ushort_t* KT16  = P4 + 4608;             // K^T[d][t]
    ushort_t* KTs16 = P4 + 2*4608;           // (K^T diag(sce))[d][t]
    ushort_t* Qb16  = P4 + 3*4608;           // Q[t][d]
    ushort_t* VT16  = P4 + 4*4608;           // V^T[v][t]
    ushort_t* Tw1   = R5;                    // (T diag(w1))[i][j]
    ushort_t* Tw2   = R5 + 4608;             // (T diag(w2))[i][j]
    ushort_t* WT16  = R5;                    // W^T[d][i]   (after Tw dead)
    ushort_t* VtT16 = R5 + 4608;             // Vt^T[v][i]

    // ---- S1: load Q,K,V f32; gamma/weights (wave 0) ----
    #pragma unroll
    for (int r = 0; r < 4; ++r) {
        int id = tid + r*256;
        int row = id >> 4;
        int dq = (id & 15) * 4;
        const float* src = &qkv_act[(size_t)(t0+row)*CONV_DIM];
        *(float4*)&Qf[row][dq] = *(const float4*)&src[hs*64 + dq];
        *(float4*)&Kf[row][dq] = *(const float4*)&src[KEY_DIM + hs*64 + dq];
        *(float4*)&Vf[row][dq] = *(const float4*)&src[2*KEY_DIM + h*64 + dq];
    }
    if (tid < 64) {
        float gv = g[(size_t)(t0+tid)*NV + h];
        float bv = beta[(size_t)(t0+tid)*NV + h];
        #pragma unroll
        for (int off = 1; off < 64; off <<= 1) {
            float n = __shfl_up(gv, off, 64);
            if (tid >= off) gv += n;
        }
        gam[tid] = gv;
        float e = expf(gv);
        egs[tid] = e;
        w1s[tid] = bv * e;
        w2s[tid] = bv;
        float gC = __shfl(gv, 63, 64);
        sces[tid] = expf(gC - gv);
        if (tid == 63) eCs = e;
    }
    __syncthreads();

    // ---- S2: l2norm q (x1/8), k in place ----
    {
        int row = tid >> 2, q4 = (tid & 3) * 16;
        float sq = 0.f, sk = 0.f;
        #pragma unroll
        for (int d = 0; d < 16; d += 4) {
            float4 qv = *(float4*)&Qf[row][q4+d];
            float4 kv = *(float4*)&Kf[row][q4+d];
            sq += qv.x*qv.x + qv.y*qv.y + qv.z*qv.z + qv.w*qv.w;
            sk += kv.x*kv.x + kv.y*kv.y + kv.z*kv.z + kv.w*kv.w;
        }
        sq += __shfl_xor(sq, 1, 64); sq += __shfl_xor(sq, 2, 64);
        sk += __shfl_xor(sk, 1, 64); sk += __shfl_xor(sk, 2, 64);
        float rq = rsqrtf(sq + 1e-6f) * 0.125f;
        float rk = rsqrtf(sk + 1e-6f);
        #pragma unroll
        for (int d = 0; d < 16; d += 4) {
            float4 qv = *(float4*)&Qf[row][q4+d];
            qv.x*=rq; qv.y*=rq; qv.z*=rq; qv.w*=rq;
            *(float4*)&Qf[row][q4+d] = qv;
            float4 kv = *(float4*)&Kf[row][q4+d];
            kv.x*=rk; kv.y*=rk; kv.z*=rk; kv.w*=rk;
            *(float4*)&Kf[row][q4+d] = kv;
        }
    }
    __syncthreads();

    // ---- S3: pack bf16 operand copies ----
    {
        int row = tid >> 2, seg = (tid & 3) * 16;
        float sc = sces[row];
        #pragma unroll
        for (int cc = 0; cc < 16; ++cc) {
            int col = seg + cc;
            float kv = Kf[row][col];
            ushort_t kb = f2bf(kv);
            Kb16[row*72 + col] = kb;
            KT16[col*72 + row] = kb;
            KTs16[col*72 + row] = f2bf(kv * sc);
            Qb16[row*72 + col] = f2bf(Qf[row][col]);
            VT16[col*72 + row] = f2bf(Vf[row][col]);
        }
    }
    __syncthreads();

    // ---- S4: A = mask_lower(w2_i e^{gi-gj} K K^T) -> Ab f32 (overlays Kf) ----
    {
        f32x4 a4[2][2];
        mm64(Kb16, Kb16, wr, wc, l, a4);
        const int rbase = wr*32 + (l>>4)*4, cbase = wc*32 + (l&15);
        #pragma unroll
        for (int fi = 0; fi < 2; ++fi)
            #pragma unroll
            for (int fj = 0; fj < 2; ++fj) {
                int j = cbase + fj*16;
                #pragma unroll
                for (int r = 0; r < 4; ++r) {
                    int i = rbase + fi*16 + r;
                    float v = (j < i) ? a4[fi][fj][r] * w2s[i] * expf(gam[i]-gam[j]) : 0.f;
                    Ab[i][j] = v;
                }
            }
    }
    __syncthreads();

    // ---- S5: T = (I+A)^{-1} forward substitution (wave 0), into Tb (overlays Vf) ----
    if (tid < 64) {
        int col = tid;
        Tb[0][col] = (col == 0) ? 1.f : 0.f;
        for (int i = 1; i < 64; ++i) {
            float acc = 0.f;
            int nf = i >> 2;
            for (int j4 = 0; j4 < nf; ++j4) {
                float4 a = *(float4*)&Ab[i][4*j4];
                int j = 4*j4;
                acc += a.x * Tb[j  ][col];
                acc += a.y * Tb[j+1][col];
                acc += a.z * Tb[j+2][col];
                acc += a.w * Tb[j+3][col];
            }
            for (int j = i & ~3; j < i; ++j) acc += Ab[i][j] * Tb[j][col];
            Tb[i][col] = ((i==col)?1.f:0.f) - acc;
        }
    }
    __syncthreads();

    // ---- S6: pack Tw1 = T diag(w1), Tw2 = T diag(w2) (bf16) ----
    {
        int row = tid >> 2, seg = (tid & 3) * 16;
        #pragma unroll
        for (int cc = 0; cc < 16; ++cc) {
            int col = seg + cc;
            float tv = Tb[row][col];
            Tw1[row*72 + col] = f2bf(tv * w1s[col]);
            Tw2[row*72 + col] = f2bf(tv * w2s[col]);
        }
    }
    __syncthreads();

    // ---- S7: W = Tw1 K, Vt = Tw2 V (into regs) ----
    f32x4 accW[2][2], accV[2][2];
    mm64(Tw1, KT16, wr, wc, l, accW);   // out[i][d]
    mm64(Tw2, VT16, wr, wc, l, accV);   // out[i][v]
    __syncthreads();                     // Tw reads complete before overwrite

    // ---- S8: write WT16[d][i], VtT16[v][i]; M = mask_upper(e^{gi-gj} Q K^T) -> M16 ----
    {
        const int rbase = wr*32 + (l>>4)*4, cbase = wc*32 + (l&15);
        #pragma unroll
        for (int fi = 0; fi < 2; ++fi)
            #pragma unroll
            for (int fj = 0; fj < 2; ++fj) {
                int dcol = cbase + fj*16;
                int ib2 = rbase + fi*16;
                store_bf16x4(&WT16[dcol*72 + ib2],
                             accW[fi][fj][0], accW[fi][fj][1], accW[fi][fj][2], accW[fi][fj][3]);
                store_bf16x4(&VtT16[dcol*72 + ib2],
                             accV[fi][fj][0], accV[fi][fj][1], accV[fi][fj][2], accV[fi][fj][3]);
            }
        f32x4 accM[2][2];
        mm64(Qb16, Kb16, wr, wc, l, accM);   // out[i][j]
        #pragma unroll
        for (int fi = 0; fi < 2; ++fi)
            #pragma unroll
            for (int fj = 0; fj < 2; ++fj) {
                int j = cbase + fj*16;
                #pragma unroll
                for (int r = 0; r < 4; ++r) {
                    int i = rbase + fi*16 + r;
                    float v = (i >= j) ? accM[fi][fj][r] * expf(gam[i]-gam[j]) : 0.f;
                    M16[i*72 + j] = f2bf(v);
                }
            }
    }
    __syncthreads();

    // ---- S9: outputs ----
    const size_t obase = (size_t)(h*NCHUNK + c) * 4096;
    const int rbase = wr*32 + (l>>4)*4, cbase = wc*32 + (l&15);
    {   // P = eC I - K^T diag(sce) W  -> PT_all[d2][d1]
        f32x4 accP[2][2];
        mm64(KTs16, WT16, wr, wc, l, accP);  // out[d1][d2]
        float eC = eCs;
        #pragma unroll
        for (int fi = 0; fi < 2; ++fi)
            #pragma unroll
            for (int fj = 0; fj < 2; ++fj) {
                int d1b = rbase + fi*16, d2 = cbase + fj*16;
                float o[4];
                #pragma unroll
                for (int r = 0; r < 4; ++r) {
                    int d1 = d1b + r;
                    o[r] = ((d1==d2) ? eC : 0.f) - accP[fi][fj][r];
                }
                *(float4*)&PT_all[obase + (size_t)d2*64 + d1b] = make_float4(o[0],o[1],o[2],o[3]);
            }
    }
    {   // B[d][v] = K^T diag(sce) Vt  (computed as out[v][d])
        f32x4 accB[2][2];
        mm64(VtT16, KTs16, wr, wc, l, accB);
        #pragma unroll
        for (int fi = 0; fi < 2; ++fi)
            #pragma unroll
            for (int fj = 0; fj < 2; ++fj) {
                int vb = rbase + fi*16, d = cbase + fj*16;
                store_bf16x4(&B_all[obase + (size_t)d*64 + vb],
                             accB[fi][fj][0], accB[fi][fj][1], accB[fi][fj][2], accB[fi][fj][3]);
            }
    }
    {   // R = diag(eg) Q - M W  -> RT_all[d][i]
        f32x4 accR[2][2];
        mm64(M16, WT16, wr, wc, l, accR);    // out[i][d]
        #pragma unroll
        for (int fi = 0; fi < 2; ++fi)
            #pragma unroll
            for (int fj = 0; fj < 2; ++fj) {
                int ibb = rbase + fi*16, d = cbase + fj*16;
                float o[4];
                #pragma unroll
                for (int r = 0; r < 4; ++r) {
                    int i = ibb + r;
                    o[r] = egs[i] * Qf[i][d] - accR[fi][fj][r];
                }
                *(float4*)&RT_all[obase + (size_t)d*64 + ibb] = make_float4(o[0],o[1],o[2],o[3]);
            }
    }
    {   // Oin[i][v] = M Vt  (computed as out[v][i])
        f32x4 accO[2][2];
        mm64(VtT16, M16, wr, wc, l, accO);
        #pragma unroll
        for (int fi = 0; fi < 2; ++fi)
            #pragma unroll
            for (int fj = 0; fj < 2; ++fj) {
                int vb = rbase + fi*16, i = cbase + fj*16;
                store_bf16x4(&Oin_all[obase + (size_t)i*64 + vb],
                             accO[fi][fj][0], accO[fi][fj][1], accO[fi][fj][2], accO[fi][fj][3]);
            }
    }
}

// ---------------- Phase 2: sequential over chunks ----------------
__global__ __launch_bounds__(256) void phase2_kernel(
    const float* __restrict__ PT_all, const ushort_t* __restrict__ B_all,
    const float* __restrict__ RT_all, const ushort_t* __restrict__ Oin_all,
    float* __restrict__ y)
{
    const int h = blockIdx.x >> 2, vg = blockIdx.x & 3;
    const int tid = threadIdx.x;
    const int wave = tid >> 6, lane = tid & 63;

    __shared__ float PT_s[2][64][68];
    __shared__ float RT_s[2][64][68];
    __shared__ float B_s[2][64][20];
    __shared__ float O_s[2][64][20];
    __shared__ float S_s[2][64][20];

    for (int i = tid; i < 64*20; i += 256) ((float*)S_s[0])[i] = 0.f;

    const size_t hb = (size_t)h * NCHUNK;

    {
        const float* Ps = PT_all + hb*4096;
        const float* Rs = RT_all + hb*4096;
        #pragma unroll
        for (int j = 0; j < 4; ++j) {
            int idx = tid + j*256;
            int row = idx >> 4, c4 = (idx & 15)*4;
            *(float4*)&PT_s[0][row][c4] = *(const float4*)&Ps[(size_t)row*64 + c4];
            *(float4*)&RT_s[0][row][c4] = *(const float4*)&Rs[(size_t)row*64 + c4];
        }
        if (tid < 128) {
            const ushort_t* Bs = B_all + hb*4096 + vg*16;
            const ushort_t* Os = Oin_all + hb*4096 + vg*16;
            int row = tid >> 1, c8 = (tid & 1)*8;
            unpack8(*(const uint4*)&Bs[(size_t)row*64 + c8], &B_s[0][row][c8]);
            unpack8(*(const uint4*)&Os[(size_t)row*64 + c8], &O_s[0][row][c8]);
        }
    }
    __syncthreads();

    for (int c = 0; c < NCHUNK; ++c) {
        const int cb = c & 1, nb = cb ^ 1;
        if (wave >= 2) {
            if (c + 1 < NCHUNK) {
                const int ll = (wave-2)*64 + lane;
                const float* Ps = PT_all + (hb + c+1)*4096;
                const float* Rs = RT_all + (hb + c+1)*4096;
                #pragma unroll
                for (int j = 0; j < 8; ++j) {
                    int idx = ll + j*128;
                    int row = idx >> 4, c4 = (idx & 15)*4;
                    *(float4*)&PT_s[nb][row][c4] = *(const float4*)&Ps[(size_t)row*64 + c4];
                    *(float4*)&RT_s[nb][row][c4] = *(const float4*)&Rs[(size_t)row*64 + c4];
                }
                const ushort_t* Bs = B_all + (hb + c+1)*4096 + vg*16;
                const ushort_t* Os = Oin_all + (hb + c+1)*4096 + vg*16;
                int row = ll >> 1, c8 = (ll & 1)*8;
                unpack8(*(const uint4*)&Bs[(size_t)row*64 + c8], &B_s[nb][row][c8]);
                unpack8(*(const uint4*)&Os[(size_t)row*64 + c8], &O_s[nb][row][c8]);
            }
        } else if (wave == 0) {
            int ti = lane >> 2, tv = lane & 3;
            float acc[4][4];
            #pragma unroll
            for (int r = 0; r < 4; ++r) {
                float4 o4 = *(float4*)&O_s[cb][4*ti+r][4*tv];
                acc[r][0]=o4.x; acc[r][1]=o4.y; acc[r][2]=o4.z; acc[r][3]=o4.w;
            }
            for (int k = 0; k < 64; ++k) {
                float4 r4 = *(float4*)&RT_s[cb][k][4*ti];
                float rr[4]={r4.x,r4.y,r4.z,r4.w};
                float4 s4 = *(float4*)&S_s[cb][k][4*tv];
                float sv[4]={s4.x,s4.y,s4.z,s4.w};
                #pragma unroll
                for (int r = 0; r < 4; ++r)
                    #pragma unroll
                    for (int s = 0; s < 4; ++s)
                        acc[r][s] += rr[r]*sv[s];
            }
            float* yr = y + (size_t)(c*64)*VAL_DIM + h*64 + vg*16;
            #pragma unroll
            for (int r = 0; r < 4; ++r)
                *(float4*)&yr[(size_t)(4*ti+r)*VAL_DIM + 4*tv] =
                    make_float4(acc[r][0],acc[r][1],acc[r][2],acc[r][3]);
        } else if (wave == 1) {
            int tk = lane >> 2, tv = lane & 3;
            float acc[4][4];
            #pragma unroll
            for (int r = 0; r < 4; ++r) {
                float4 b4 = *(float4*)&B_s[cb][4*tk+r][4*tv];
                acc[r][0]=b4.x; acc[r][1]=b4.y; acc[r][2]=b4.z; acc[r][3]=b4.w;
            }
            for (int k2 = 0; k2 < 64; ++k2) {
                float4 p4 = *(float4*)&PT_s[cb][k2][4*tk];
                float pp[4]={p4.x,p4.y,p4.z,p4.w};
                float4 s4 = *(float4*)&S_s[cb][k2][4*tv];
                float sv[4]={s4.x,s4.y,s4.z,s4.w};
                #pragma unroll
                for (int r = 0; r < 4; ++r)
                    #pragma unroll
                    for (int s = 0; s < 4; ++s)
                        acc[r][s] += pp[r]*sv[s];
            }
            #pragma unroll
            for (int r = 0; r < 4; ++r)
                *(float4*)&S_s[nb][4*tk+r][4*tv] =
                    make_float4(acc[r][0],acc[r][1],acc[r][2],acc[r][3]);
        }
        __syncthreads();
    }
}

// ---------------- RMSNorm(dv) * norm_weight * silu(z)  -> bf16 ----------------
__global__ __launch_bounds__(256) void rmsnorm_gate_kernel(
    const float* __restrict__ y, const float* __restrict__ z,
    const float* __restrict__ nw, ushort_t* __restrict__ yn)
{
    int row = blockIdx.x * 4 + (threadIdx.x >> 6);
    int lane = threadIdx.x & 63;
    float v = y[(size_t)row*64 + lane];
    float ss = v*v;
    #pragma unroll
    for (int off = 1; off < 64; off <<= 1) ss += __shfl_xor(ss, off, 64);
    float rn = rsqrtf(ss * (1.f/64.f) + 1e-6f);
    float zz = z[(size_t)row*64 + lane];
    yn[(size_t)row*64 + lane] = f2bf(nw[lane] * v * rn * (zz / (1.f + expf(-zz))));
}

extern "C" void kernel_launch(void* const* d_in, const int* in_sizes, int n_in,
                              void* d_out, int out_size, void* d_ws, size_t ws_size,
                              hipStream_t stream)
{
    const float* x      = (const float*)d_in[0];
    const float* W_qkv  = (const float*)d_in[1];
    const float* W_z    = (const float*)d_in[2];
    const float* W_b    = (const float*)d_in[3];
    const float* W_a    = (const float*)d_in[4];
    const float* W_out  = (const float*)d_in[5];
    const float* conv_w = (const float*)d_in[6];
    const float* dt_b   = (const float*)d_in[7];
    const float* A_log  = (const float*)d_in[8];
    const float* nw     = (const float*)d_in[9];
    float* out = (float*)d_out;

    float* ws = (float*)d_ws;
    const size_t M1 = 1u << 20;
    float* qkv_raw   = ws;
    float* PT_all    = ws;
    ushort_t* B_all   = (ushort_t*)(ws + 2*M1);
    ushort_t* Oin_all = (ushort_t*)(ws + 3*M1);
    float* qkv_act   = ws + 4*M1;
    ushort_t* yn_bf   = (ushort_t*)(ws + 4*M1);
    ushort_t* Wout_bf = (ushort_t*)(ws + 5*M1);
    float* y_buf     = ws + 6*M1;
    ushort_t* x_bf    = (ushort_t*)(ws + 6*M1);
    ushort_t* Wqkv_bf = (ushort_t*)(ws + 8*M1);
    float* z_buf     = ws + 8*M1;
    ushort_t* Wz_bf   = (ushort_t*)(ws + 10*M1);
    float* RT_all    = ws + 10*M1;
    float* beta      = ws + 12*M1;
    float* g_buf     = ws + 12*M1 + 32768;

    dim3 blk(256);
    f32_to_bf16_kernel<<<dim3(2048), blk, 0, stream>>>(x, x_bf);
    f32_to_bf16_kernel<<<dim3(2048), blk, 0, stream>>>(W_qkv, Wqkv_bf);
    f32_to_bf16_kernel<<<dim3(1024), blk, 0, stream>>>(W_z, Wz_bf);
    gemm_bt_bf16<<<dim3(CONV_DIM/128, T_LEN/128), blk, 0, stream>>>(
        T_LEN, CONV_DIM, DIM, x_bf, Wqkv_bf, qkv_raw);
    gemm_bt_bf16<<<dim3(VAL_DIM/128, T_LEN/128), blk, 0, stream>>>(
        T_LEN, VAL_DIM, DIM, x_bf, Wz_bf, z_buf);
    betag_kernel<<<dim3(T_LEN), blk, 0, stream>>>(x, W_b, W_a, dt_b, A_log, beta, g_buf);
    conv_silu_kernel<<<dim3(CONV_DIM/256, T_LEN), blk, 0, stream>>>(qkv_raw, conv_w, qkv_act);
    phase1_kernel<<<dim3(NV*NCHUNK), blk, 0, stream>>>(
        qkv_act, g_buf, beta, PT_all, B_all, RT_all, Oin_all);
    phase2_kernel<<<dim3(NV*4), blk, 0, stream>>>(PT_all, B_all, RT_all, Oin_all, y_buf);
    rmsnorm_gate_kernel<<<dim3(T_LEN*NV/4), blk, 0, stream>>>(y_buf, z_buf, nw, yn_bf);
    f32_to_bf16_kernel<<<dim3(1024), blk, 0, stream>>>(W_out, Wout_bf);
    gemm_bt_bf16<<<dim3(DIM/128, T_LEN/128), blk, 0, stream>>>(
        T_LEN, DIM, VAL_DIM, yn_bf, Wout_bf, out);
}

// Round 9
// 422.104 us; speedup vs baseline: 3.7956x; 1.1743x over previous
//
#include <hip/hip_runtime.h>
#include <hip/hip_bf16.h>
#include <math.h>

#define T_LEN 2048
#define DIM 2048
#define CONV_DIM 2048
#define KEY_DIM 512
#define VAL_DIM 1024
#define NK 8
#define NV 16
#define NCHUNK 32
#define NEXT 2176   // CONV_DIM + 128 (32 beta/g cols + 96 pad)

typedef unsigned short ushort_t;
typedef __bf16 bf16x8 __attribute__((ext_vector_type(8)));
typedef float f32x4 __attribute__((ext_vector_type(4)));

// ---------------- helpers ----------------
static __device__ __forceinline__ void unpack8(uint4 raw, float* dst) {
    dst[0] = __uint_as_float(raw.x << 16);
    dst[1] = __uint_as_float(raw.x & 0xffff0000u);
    dst[2] = __uint_as_float(raw.y << 16);
    dst[3] = __uint_as_float(raw.y & 0xffff0000u);
    dst[4] = __uint_as_float(raw.z << 16);
    dst[5] = __uint_as_float(raw.z & 0xffff0000u);
    dst[6] = __uint_as_float(raw.w << 16);
    dst[7] = __uint_as_float(raw.w & 0xffff0000u);
}
static __device__ __forceinline__ unsigned short f2bf(float f) {
    unsigned int u = __float_as_uint(f);
    unsigned int r = (u + 0x7fffu + ((u >> 16) & 1u)) >> 16;
    return (unsigned short)r;
}
static __device__ __forceinline__ void store_bf16x4(ushort_t* dst, float a, float b, float c, float d) {
    union { unsigned short h[4]; uint2 u; } p;
    p.h[0] = f2bf(a); p.h[1] = f2bf(b); p.h[2] = f2bf(c); p.h[3] = f2bf(d);
    *(uint2*)dst = p.u;
}

#define GL2LDS(g, l) __builtin_amdgcn_global_load_lds( \
    (const __attribute__((address_space(1))) void*)(g), \
    (__attribute__((address_space(3))) void*)(l), 16, 0, 0)

// 64x64x64 X*Y^T on MFMA: X,Y bf16 LDS [64][72] row-major (X: [row][k], Y: [col][k]).
static __device__ __forceinline__ void mm64(
    const ushort_t* X, const ushort_t* Y, int wr, int wc, int l, f32x4 acc[2][2])
{
    const int rr = l & 15, kq = (l >> 4) * 8;
    #pragma unroll
    for (int i = 0; i < 2; ++i)
        #pragma unroll
        for (int j = 0; j < 2; ++j)
            #pragma unroll
            for (int r = 0; r < 4; ++r) acc[i][j][r] = 0.f;
    #pragma unroll
    for (int t = 0; t < 2; ++t) {
        bf16x8 a[2], b[2];
        #pragma unroll
        for (int i = 0; i < 2; ++i)
            a[i] = *(const bf16x8*)&X[(wr*32 + i*16 + rr)*72 + t*32 + kq];
        #pragma unroll
        for (int j = 0; j < 2; ++j)
            b[j] = *(const bf16x8*)&Y[(wc*32 + j*16 + rr)*72 + t*32 + kq];
        #pragma unroll
        for (int i = 0; i < 2; ++i)
            #pragma unroll
            for (int j = 0; j < 2; ++j)
                acc[i][j] = __builtin_amdgcn_mfma_f32_16x16x32_bf16(a[i], b[j], acc[i][j], 0, 0, 0);
    }
}

// ---------------- f32 -> bf16 conversion (8 elems/thread) ----------------
__global__ __launch_bounds__(256) void f32_to_bf16_kernel(
    const float* __restrict__ in, ushort_t* __restrict__ out)
{
    size_t i = ((size_t)blockIdx.x * 256 + threadIdx.x) * 8;
    float4 v0 = *(const float4*)&in[i];
    float4 v1 = *(const float4*)&in[i + 4];
    union { unsigned short h[8]; uint4 u; } p;
    p.h[0]=f2bf(v0.x); p.h[1]=f2bf(v0.y); p.h[2]=f2bf(v0.z); p.h[3]=f2bf(v0.w);
    p.h[4]=f2bf(v1.x); p.h[5]=f2bf(v1.y); p.h[6]=f2bf(v1.z); p.h[7]=f2bf(v1.w);
    *(uint4*)&out[i] = p.u;
}

// ---------------- GEMM: C[M,*] = A[M,K] @ W[N,K]^T  (bf16 MFMA, split epilogue) ----------------
// Column tiles with n0 <  nsplit -> C  (row stride nsplit, col offset n0)
//              with n0 >= nsplit -> C2 (row stride N-nsplit, col offset n0-nsplit)
// Plain GEMM: pass nsplit = N (C2 unused).
__global__ __launch_bounds__(256) void gemm_bt_bf16(
    int M, int N, int K,
    const ushort_t* __restrict__ A,
    const ushort_t* __restrict__ W,
    float* __restrict__ C, float* __restrict__ C2, int nsplit)
{
    __shared__ __align__(16) ushort_t As[128 * 32];
    __shared__ __align__(16) ushort_t Bs[128 * 32];
    const int tid = threadIdx.x;
    const int l = tid & 63;
    const int w = tid >> 6;
    const int wr = w >> 1, wc = w & 1;
    const int m0 = blockIdx.y * 128, n0 = blockIdx.x * 128;

    f32x4 acc[4][4];
    #pragma unroll
    for (int i = 0; i < 4; ++i)
        #pragma unroll
        for (int j = 0; j < 4; ++j)
            #pragma unroll
            for (int r = 0; r < 4; ++r) acc[i][j][r] = 0.f;

    const int srow = w * 16 + (l >> 2);
    const int scol = (l & 3) * 8;
    const ushort_t* gA0 = A + (size_t)(m0 + srow) * K + scol;
    const ushort_t* gA1 = A + (size_t)(m0 + 64 + srow) * K + scol;
    const ushort_t* gB0 = W + (size_t)(n0 + srow) * K + scol;
    const ushort_t* gB1 = W + (size_t)(n0 + 64 + srow) * K + scol;
    ushort_t* lA0 = &As[(w * 16) * 32];
    ushort_t* lA1 = &As[(64 + w * 16) * 32];
    ushort_t* lB0 = &Bs[(w * 16) * 32];
    ushort_t* lB1 = &Bs[(64 + w * 16) * 32];

    const int kq = (l >> 4) * 8;
    const int rr = l & 15;

    for (int k0 = 0; k0 < K; k0 += 32) {
        __syncthreads();
        GL2LDS(gA0 + k0, lA0);
        GL2LDS(gA1 + k0, lA1);
        GL2LDS(gB0 + k0, lB0);
        GL2LDS(gB1 + k0, lB1);
        __syncthreads();
        bf16x8 af[4], bf[4];
        #pragma unroll
        for (int i = 0; i < 4; ++i) {
            af[i] = *(const bf16x8*)&As[(wr * 64 + i * 16 + rr) * 32 + kq];
            bf[i] = *(const bf16x8*)&Bs[(wc * 64 + i * 16 + rr) * 32 + kq];
        }
        #pragma unroll
        for (int i = 0; i < 4; ++i)
            #pragma unroll
            for (int j = 0; j < 4; ++j)
                acc[i][j] = __builtin_amdgcn_mfma_f32_16x16x32_bf16(af[i], bf[j], acc[i][j], 0, 0, 0);
    }

    // epilogue with block-uniform destination split
    const int crow = (l >> 4) * 4, ccol = l & 15;
    float* Cb; int stride, coff;
    if (n0 < nsplit) { Cb = C;  stride = nsplit;      coff = n0; }
    else             { Cb = C2; stride = N - nsplit;  coff = n0 - nsplit; }
    #pragma unroll
    for (int i = 0; i < 4; ++i)
        #pragma unroll
        for (int j = 0; j < 4; ++j) {
            float* cp = &Cb[(size_t)(m0 + wr * 64 + i * 16 + crow) * stride + coff + wc * 64 + j * 16 + ccol];
            #pragma unroll
            for (int r = 0; r < 4; ++r) cp[(size_t)r * stride] = acc[i][j][r];
        }
}

// ---------------- beta/g from GEMM output ----------------
// bg[t][0..15] = pre-sigmoid beta, bg[t][16..31] = pre-softplus g (row stride 128)
__global__ __launch_bounds__(256) void betag_apply_kernel(
    const float* __restrict__ bg, const float* __restrict__ dt_bias,
    const float* __restrict__ A_log,
    float* __restrict__ beta, float* __restrict__ g)
{
    int idx = blockIdx.x * 256 + threadIdx.x;   // 0 .. 2048*32-1
    int t = idx >> 5, c = idx & 31;
    float s = bg[(size_t)t * 128 + c];
    if (c < NV) {
        beta[(size_t)t * NV + c] = 1.f / (1.f + expf(-s));
    } else {
        int n = c - NV;
        float sp = s + dt_bias[n];
        sp = (sp > 20.f) ? sp : log1pf(expf(sp));
        g[(size_t)t * NV + n] = -expf(A_log[n]) * sp;
    }
}

// ---------------- causal depthwise conv (K=4) + SiLU ----------------
__global__ __launch_bounds__(256) void conv_silu_kernel(
    const float* __restrict__ qkv_raw,
    const float* __restrict__ conv_w,
    float* __restrict__ qkv_act)
{
    int c = blockIdx.x * 256 + threadIdx.x;
    int t = blockIdx.y;
    float4 w = ((const float4*)conv_w)[c];
    float s = 0.f;
    if (t >= 3) s += qkv_raw[(size_t)(t-3)*CONV_DIM + c] * w.x;
    if (t >= 2) s += qkv_raw[(size_t)(t-2)*CONV_DIM + c] * w.y;
    if (t >= 1) s += qkv_raw[(size_t)(t-1)*CONV_DIM + c] * w.z;
    s += qkv_raw[(size_t)t*CONV_DIM + c] * w.w;
    qkv_act[(size_t)t*CONV_DIM + c] = s / (1.f + expf(-s));
}

// ---------------- Phase 1 (MFMA): per (head, chunk) WY factors -> P, B, R, Oin ----------------
__global__ __launch_bounds__(256) void phase1_kernel(
    const float* __restrict__ qkv_act,
    const float* __restrict__ g, const float* __restrict__ beta,
    float* __restrict__ PT_all, ushort_t* __restrict__ B_all,
    float* __restrict__ RT_all, ushort_t* __restrict__ Oin_all)
{
    const int hc = blockIdx.x;
    const int h = hc >> 5, c = hc & 31;
    const int hs = h >> 1;
    const int tid = threadIdx.x;
    const int l = tid & 63, w = tid >> 6;
    const int wr = w >> 1, wc = w & 1;
    const int t0 = c * 64;

    __shared__ float Qf[64][68];                       // persists (R epilogue)
    __shared__ __align__(16) float R1f[64*68];         // Kf -> Ab
    __shared__ __align__(16) float R2f[64*68];         // Vf -> Tb -> M16
    __shared__ __align__(16) ushort_t P4[5*64*72];     // Kb16,KT16,KTs16,Qb16,VT16
    __shared__ __align__(16) ushort_t R5[2*64*72];     // Tw1,Tw2 -> WT16,VtT16
    __shared__ float gam[64], w1s[64], w2s[64], sces[64], egs[64];
    __shared__ float eCs;

    float (*Kf)[68] = (float(*)[68])R1f;
    float (*Ab)[68] = (float(*)[68])R1f;
    float (*Vf)[68] = (float(*)[68])R2f;
    float (*Tb)[68] = (float(*)[68])R2f;
    ushort_t* M16   = (ushort_t*)R2f;
    ushort_t* Kb16  = P4;
    ushort_t* KT16  = P4 + 4608;
    ushort_t* KTs16 = P4 + 2*4608;
    ushort_t* Qb16  = P4 + 3*4608;
    ushort_t* VT16  = P4 + 4*4608;
    ushort_t* Tw1   = R5;
    ushort_t* Tw2   = R5 + 4608;
    ushort_t* WT16  = R5;
    ushort_t* VtT16 = R5 + 4608;

    // ---- S1: load Q,K,V f32; gamma/weights (wave 0) ----
    #pragma unroll
    for (int r = 0; r < 4; ++r) {
        int id = tid + r*256;
        int row = id >> 4;
        int dq = (id & 15) * 4;
        const float* src = &qkv_act[(size_t)(t0+row)*CONV_DIM];
        *(float4*)&Qf[row][dq] = *(const float4*)&src[hs*64 + dq];
        *(float4*)&Kf[row][dq] = *(const float4*)&src[KEY_DIM + hs*64 + dq];
        *(float4*)&Vf[row][dq] = *(const float4*)&src[2*KEY_DIM + h*64 + dq];
    }
    if (tid < 64) {
        float gv = g[(size_t)(t0+tid)*NV + h];
        float bv = beta[(size_t)(t0+tid)*NV + h];
        #pragma unroll
        for (int off = 1; off < 64; off <<= 1) {
            float n = __shfl_up(gv, off, 64);
            if (tid >= off) gv += n;
        }
        gam[tid] = gv;
        float e = expf(gv);
        egs[tid] = e;
        w1s[tid] = bv * e;
        w2s[tid] = bv;
        float gC = __shfl(gv, 63, 64);
        sces[tid] = expf(gC - gv);
        if (tid == 63) eCs = e;
    }
    __syncthreads();

    // ---- S2: l2norm q (x1/8), k in place ----
    {
        int row = tid >> 2, q4 = (tid & 3) * 16;
        float sq = 0.f, sk = 0.f;
        #pragma unroll
        for (int d = 0; d < 16; d += 4) {
            float4 qv = *(float4*)&Qf[row][q4+d];
            float4 kv = *(float4*)&Kf[row][q4+d];
            sq += qv.x*qv.x + qv.y*qv.y + qv.z*qv.z + qv.w*qv.w;
            sk += kv.x*kv.x + kv.y*kv.y + kv.z*kv.z + kv.w*kv.w;
        }
        sq += __shfl_xor(sq, 1, 64); sq += __shfl_xor(sq, 2, 64);
        sk += __shfl_xor(sk, 1, 64); sk += __shfl_xor(sk, 2, 64);
        float rq = rsqrtf(sq + 1e-6f) * 0.125f;
        float rk = rsqrtf(sk + 1e-6f);
        #pragma unroll
        for (int d = 0; d < 16; d += 4) {
            float4 qv = *(float4*)&Qf[row][q4+d];
            qv.x*=rq; qv.y*=rq; qv.z*=rq; qv.w*=rq;
            *(float4*)&Qf[row][q4+d] = qv;
            float4 kv = *(float4*)&Kf[row][q4+d];
            kv.x*=rk; kv.y*=rk; kv.z*=rk; kv.w*=rk;
            *(float4*)&Kf[row][q4+d] = kv;
        }
    }
    __syncthreads();

    // ---- S3: pack bf16 operand copies ----
    {
        int row = tid >> 2, seg = (tid & 3) * 16;
        float sc = sces[row];
        #pragma unroll
        for (int cc = 0; cc < 16; ++cc) {
            int col = seg + cc;
            float kv = Kf[row][col];
            ushort_t kb = f2bf(kv);
            Kb16[row*72 + col] = kb;
            KT16[col*72 + row] = kb;
            KTs16[col*72 + row] = f2bf(kv * sc);
            Qb16[row*72 + col] = f2bf(Qf[row][col]);
            VT16[col*72 + row] = f2bf(Vf[row][col]);
        }
    }
    __syncthreads();

    // ---- S4: A = mask_lower(w2_i e^{gi-gj} K K^T) -> Ab f32 (overlays Kf) ----
    {
        f32x4 a4[2][2];
        mm64(Kb16, Kb16, wr, wc, l, a4);
        const int rbase = wr*32 + (l>>4)*4, cbase = wc*32 + (l&15);
        #pragma unroll
        for (int fi = 0; fi < 2; ++fi)
            #pragma unroll
            for (int fj = 0; fj < 2; ++fj) {
                int j = cbase + fj*16;
                #pragma unroll
                for (int r = 0; r < 4; ++r) {
                    int i = rbase + fi*16 + r;
                    float v = (j < i) ? a4[fi][fj][r] * w2s[i] * expf(gam[i]-gam[j]) : 0.f;
                    Ab[i][j] = v;
                }
            }
    }
    __syncthreads();

    // ---- S5: T = (I+A)^{-1} forward substitution (wave 0), into Tb (overlays Vf) ----
    if (tid < 64) {
        int col = tid;
        Tb[0][col] = (col == 0) ? 1.f : 0.f;
        for (int i = 1; i < 64; ++i) {
            float acc = 0.f;
            int nf = i >> 2;
            for (int j4 = 0; j4 < nf; ++j4) {
                float4 a = *(float4*)&Ab[i][4*j4];
                int j = 4*j4;
                acc += a.x * Tb[j  ][col];
                acc += a.y * Tb[j+1][col];
                acc += a.z * Tb[j+2][col];
                acc += a.w * Tb[j+3][col];
            }
            for (int j = i & ~3; j < i; ++j) acc += Ab[i][j] * Tb[j][col];
            Tb[i][col] = ((i==col)?1.f:0.f) - acc;
        }
    }
    __syncthreads();

    // ---- S6: pack Tw1 = T diag(w1), Tw2 = T diag(w2) (bf16) ----
    {
        int row = tid >> 2, seg = (tid & 3) * 16;
        #pragma unroll
        for (int cc = 0; cc < 16; ++cc) {
            int col = seg + cc;
            float tv = Tb[row][col];
            Tw1[row*72 + col] = f2bf(tv * w1s[col]);
            Tw2[row*72 + col] = f2bf(tv * w2s[col]);
        }
    }
    __syncthreads();

    // ---- S7: W = Tw1 K, Vt = Tw2 V (into regs) ----
    f32x4 accW[2][2], accV[2][2];
    mm64(Tw1, KT16, wr, wc, l, accW);   // out[i][d]
    mm64(Tw2, VT16, wr, wc, l, accV);   // out[i][v]
    __syncthreads();

    // ---- S8: write WT16[d][i], VtT16[v][i]; M = mask_upper(e^{gi-gj} Q K^T) -> M16 ----
    {
        const int rbase = wr*32 + (l>>4)*4, cbase = wc*32 + (l&15);
        #pragma unroll
        for (int fi = 0; fi < 2; ++fi)
            #pragma unroll
            for (int fj = 0; fj < 2; ++fj) {
                int dcol = cbase + fj*16;
                int ib2 = rbase + fi*16;
                store_bf16x4(&WT16[dcol*72 + ib2],
                             accW[fi][fj][0], accW[fi][fj][1], accW[fi][fj][2], accW[fi][fj][3]);
                store_bf16x4(&VtT16[dcol*72 + ib2],
                             accV[fi][fj][0], accV[fi][fj][1], accV[fi][fj][2], accV[fi][fj][3]);
            }
        f32x4 accM[2][2];
        mm64(Qb16, Kb16, wr, wc, l, accM);   // out[i][j]
        #pragma unroll
        for (int fi = 0; fi < 2; ++fi)
            #pragma unroll
            for (int fj = 0; fj < 2; ++fj) {
                int j = cbase + fj*16;
                #pragma unroll
                for (int r = 0; r < 4; ++r) {
                    int i = rbase + fi*16 + r;
                    float v = (i >= j) ? accM[fi][fj][r] * expf(gam[i]-gam[j]) : 0.f;
                    M16[i*72 + j] = f2bf(v);
                }
            }
    }
    __syncthreads();

    // ---- S9: outputs ----
    const size_t obase = (size_t)(h*NCHUNK + c) * 4096;
    const int rbase = wr*32 + (l>>4)*4, cbase = wc*32 + (l&15);
    {   // P = eC I - K^T diag(sce) W  -> PT_all[d2][d1]
        f32x4 accP[2][2];
        mm64(KTs16, WT16, wr, wc, l, accP);  // out[d1][d2]
        float eC = eCs;
        #pragma unroll
        for (int fi = 0; fi < 2; ++fi)
            #pragma unroll
            for (int fj = 0; fj < 2; ++fj) {
                int d1b = rbase + fi*16, d2 = cbase + fj*16;
                float o[4];
                #pragma unroll
                for (int r = 0; r < 4; ++r) {
                    int d1 = d1b + r;
                    o[r] = ((d1==d2) ? eC : 0.f) - accP[fi][fj][r];
                }
                *(float4*)&PT_all[obase + (size_t)d2*64 + d1b] = make_float4(o[0],o[1],o[2],o[3]);
            }
    }
    {   // B[d][v] = K^T diag(sce) Vt  (computed as out[v][d])
        f32x4 accB[2][2];
        mm64(VtT16, KTs16, wr, wc, l, accB);
        #pragma unroll
        for (int fi = 0; fi < 2; ++fi)
            #pragma unroll
            for (int fj = 0; fj < 2; ++fj) {
                int vb = rbase + fi*16, d = cbase + fj*16;
                store_bf16x4(&B_all[obase + (size_t)d*64 + vb],
                             accB[fi][fj][0], accB[fi][fj][1], accB[fi][fj][2], accB[fi][fj][3]);
            }
    }
    {   // R = diag(eg) Q - M W  -> RT_all[d][i]
        f32x4 accR[2][2];
        mm64(M16, WT16, wr, wc, l, accR);    // out[i][d]
        #pragma unroll
        for (int fi = 0; fi < 2; ++fi)
            #pragma unroll
            for (int fj = 0; fj < 2; ++fj) {
                int ibb = rbase + fi*16, d = cbase + fj*16;
                float o[4];
                #pragma unroll
                for (int r = 0; r < 4; ++r) {
                    int i = ibb + r;
                    o[r] = egs[i] * Qf[i][d] - accR[fi][fj][r];
                }
                *(float4*)&RT_all[obase + (size_t)d*64 + ibb] = make_float4(o[0],o[1],o[2],o[3]);
            }
    }
    {   // Oin[i][v] = M Vt  (computed as out[v][i])
        f32x4 accO[2][2];
        mm64(VtT16, M16, wr, wc, l, accO);
        #pragma unroll
        for (int fi = 0; fi < 2; ++fi)
            #pragma unroll
            for (int fj = 0; fj < 2; ++fj) {
                int vb = rbase + fi*16, i = cbase + fj*16;
                store_bf16x4(&Oin_all[obase + (size_t)i*64 + vb],
                             accO[fi][fj][0], accO[fi][fj][1], accO[fi][fj][2], accO[fi][fj][3]);
            }
    }
}

// ---------------- Phase 2: sequential over chunks ----------------
__global__ __launch_bounds__(256) void phase2_kernel(
    const float* __restrict__ PT_all, const ushort_t* __restrict__ B_all,
    const float* __restrict__ RT_all, const ushort_t* __restrict__ Oin_all,
    float* __restrict__ y)
{
    const int h = blockIdx.x >> 2, vg = blockIdx.x & 3;
    const int tid = threadIdx.x;
    const int wave = tid >> 6, lane = tid & 63;

    __shared__ float PT_s[2][64][68];
    __shared__ float RT_s[2][64][68];
    __shared__ float B_s[2][64][20];
    __shared__ float O_s[2][64][20];
    __shared__ float S_s[2][64][20];

    for (int i = tid; i < 64*20; i += 256) ((float*)S_s[0])[i] = 0.f;

    const size_t hb = (size_t)h * NCHUNK;

    {
        const float* Ps = PT_all + hb*4096;
        const float* Rs = RT_all + hb*4096;
        #pragma unroll
        for (int j = 0; j < 4; ++j) {
            int idx = tid + j*256;
            int row = idx >> 4, c4 = (idx & 15)*4;
            *(float4*)&PT_s[0][row][c4] = *(const float4*)&Ps[(size_t)row*64 + c4];
            *(float4*)&RT_s[0][row][c4] = *(const float4*)&Rs[(size_t)row*64 + c4];
        }
        if (tid < 128) {
            const ushort_t* Bs = B_all + hb*4096 + vg*16;
            const ushort_t* Os = Oin_all + hb*4096 + vg*16;
            int row = tid >> 1, c8 = (tid & 1)*8;
            unpack8(*(const uint4*)&Bs[(size_t)row*64 + c8], &B_s[0][row][c8]);
            unpack8(*(const uint4*)&Os[(size_t)row*64 + c8], &O_s[0][row][c8]);
        }
    }
    __syncthreads();

    for (int c = 0; c < NCHUNK; ++c) {
        const int cb = c & 1, nb = cb ^ 1;
        if (wave >= 2) {
            if (c + 1 < NCHUNK) {
                const int ll = (wave-2)*64 + lane;
                const float* Ps = PT_all + (hb + c+1)*4096;
                const float* Rs = RT_all + (hb + c+1)*4096;
                #pragma unroll
                for (int j = 0; j < 8; ++j) {
                    int idx = ll + j*128;
                    int row = idx >> 4, c4 = (idx & 15)*4;
                    *(float4*)&PT_s[nb][row][c4] = *(const float4*)&Ps[(size_t)row*64 + c4];
                    *(float4*)&RT_s[nb][row][c4] = *(const float4*)&Rs[(size_t)row*64 + c4];
                }
                const ushort_t* Bs = B_all + (hb + c+1)*4096 + vg*16;
                const ushort_t* Os = Oin_all + (hb + c+1)*4096 + vg*16;
                int row = ll >> 1, c8 = (ll & 1)*8;
                unpack8(*(const uint4*)&Bs[(size_t)row*64 + c8], &B_s[nb][row][c8]);
                unpack8(*(const uint4*)&Os[(size_t)row*64 + c8], &O_s[nb][row][c8]);
            }
        } else if (wave == 0) {
            int ti = lane >> 2, tv = lane & 3;
            float acc[4][4];
            #pragma unroll
            for (int r = 0; r < 4; ++r) {
                float4 o4 = *(float4*)&O_s[cb][4*ti+r][4*tv];
                acc[r][0]=o4.x; acc[r][1]=o4.y; acc[r][2]=o4.z; acc[r][3]=o4.w;
            }
            for (int k = 0; k < 64; ++k) {
                float4 r4 = *(float4*)&RT_s[cb][k][4*ti];
                float rr[4]={r4.x,r4.y,r4.z,r4.w};
                float4 s4 = *(float4*)&S_s[cb][k][4*tv];
                float sv[4]={s4.x,s4.y,s4.z,s4.w};
                #pragma unroll
                for (int r = 0; r < 4; ++r)
                    #pragma unroll
                    for (int s = 0; s < 4; ++s)
                        acc[r][s] += rr[r]*sv[s];
            }
            float* yr = y + (size_t)(c*64)*VAL_DIM + h*64 + vg*16;
            #pragma unroll
            for (int r = 0; r < 4; ++r)
                *(float4*)&yr[(size_t)(4*ti+r)*VAL_DIM + 4*tv] =
                    make_float4(acc[r][0],acc[r][1],acc[r][2],acc[r][3]);
        } else if (wave == 1) {
            int tk = lane >> 2, tv = lane & 3;
            float acc[4][4];
            #pragma unroll
            for (int r = 0; r < 4; ++r) {
                float4 b4 = *(float4*)&B_s[cb][4*tk+r][4*tv];
                acc[r][0]=b4.x; acc[r][1]=b4.y; acc[r][2]=b4.z; acc[r][3]=b4.w;
            }
            for (int k2 = 0; k2 < 64; ++k2) {
                float4 p4 = *(float4*)&PT_s[cb][k2][4*tk];
                float pp[4]={p4.x,p4.y,p4.z,p4.w};
                float4 s4 = *(float4*)&S_s[cb][k2][4*tv];
                float sv[4]={s4.x,s4.y,s4.z,s4.w};
                #pragma unroll
                for (int r = 0; r < 4; ++r)
                    #pragma unroll
                    for (int s = 0; s < 4; ++s)
                        acc[r][s] += pp[r]*sv[s];
            }
            #pragma unroll
            for (int r = 0; r < 4; ++r)
                *(float4*)&S_s[nb][4*tk+r][4*tv] =
                    make_float4(acc[r][0],acc[r][1],acc[r][2],acc[r][3]);
        }
        __syncthreads();
    }
}

// ---------------- RMSNorm(dv) * norm_weight * silu(z)  -> bf16 ----------------
__global__ __launch_bounds__(256) void rmsnorm_gate_kernel(
    const float* __restrict__ y, const float* __restrict__ z,
    const float* __restrict__ nw, ushort_t* __restrict__ yn)
{
    int row = blockIdx.x * 4 + (threadIdx.x >> 6);
    int lane = threadIdx.x & 63;
    float v = y[(size_t)row*64 + lane];
    float ss = v*v;
    #pragma unroll
    for (int off = 1; off < 64; off <<= 1) ss += __shfl_xor(ss, off, 64);
    float rn = rsqrtf(ss * (1.f/64.f) + 1e-6f);
    float zz = z[(size_t)row*64 + lane];
    yn[(size_t)row*64 + lane] = f2bf(nw[lane] * v * rn * (zz / (1.f + expf(-zz))));
}

extern "C" void kernel_launch(void* const* d_in, const int* in_sizes, int n_in,
                              void* d_out, int out_size, void* d_ws, size_t ws_size,
                              hipStream_t stream)
{
    const float* x      = (const float*)d_in[0];
    const float* W_qkv  = (const float*)d_in[1];
    const float* W_z    = (const float*)d_in[2];
    const float* W_b    = (const float*)d_in[3];
    const float* W_a    = (const float*)d_in[4];
    const float* W_out  = (const float*)d_in[5];
    const float* conv_w = (const float*)d_in[6];
    const float* dt_b   = (const float*)d_in[7];
    const float* A_log  = (const float*)d_in[8];
    const float* nw     = (const float*)d_in[9];
    float* out = (float*)d_out;

    float* ws = (float*)d_ws;
    const size_t M1 = 1u << 20;
    // [0,4M): qkv_raw (GEMM1 out) -> after phase1: PT(0..2M) B(2..3M) Oin(3..4M)
    float* qkv_raw   = ws;
    float* PT_all    = ws;
    ushort_t* B_all   = (ushort_t*)(ws + 2*M1);
    ushort_t* Oin_all = (ushort_t*)(ws + 3*M1);
    // [4M,8M): qkv_act (until phase1) -> yn_bf [4M,5M), Wout_bf [5M,6M), y [6M,8M)
    float* qkv_act   = ws + 4*M1;
    ushort_t* yn_bf   = (ushort_t*)(ws + 4*M1);
    ushort_t* Wout_bf = (ushort_t*)(ws + 5*M1);
    float* y_buf     = ws + 6*M1;
    ushort_t* x_bf    = (ushort_t*)(ws + 6*M1);        // until GEMM2
    // [8M,10.125M): Wqkvba_bf (2176x2048 bf16, GEMM1 only) -> z_buf [8M,10M) (GEMM2 out)
    ushort_t* Wqkvba_bf = (ushort_t*)(ws + 8*M1);
    float* z_buf     = ws + 8*M1;
    // [10.25M,11.25M): Wz_bf (until GEMM2) -> RT_all [10M,12M) (phase1 out)
    ushort_t* Wz_bf   = (ushort_t*)(ws + 10*M1 + M1/4);
    float* RT_all    = ws + 10*M1;
    // [11.25M,11.5M): bg_raw (GEMM1 -> betag_apply; dead before phase1 writes RT)
    float* bg_raw    = ws + 11*M1 + M1/4;
    float* beta      = ws + 12*M1;
    float* g_buf     = ws + 12*M1 + 32768;

    dim3 blk(256);
    // 0) convert inputs to bf16
    f32_to_bf16_kernel<<<dim3(2048), blk, 0, stream>>>(x, x_bf);
    f32_to_bf16_kernel<<<dim3(2048), blk, 0, stream>>>(W_qkv, Wqkvba_bf);                   // rows 0..2047
    f32_to_bf16_kernel<<<dim3(16),   blk, 0, stream>>>(W_b, Wqkvba_bf + (size_t)2048*2048); // rows 2048..2063
    f32_to_bf16_kernel<<<dim3(16),   blk, 0, stream>>>(W_a, Wqkvba_bf + (size_t)2064*2048); // rows 2064..2079
    f32_to_bf16_kernel<<<dim3(1024), blk, 0, stream>>>(W_z, Wz_bf);
    // 1) [qkv | bg] = x @ [W_qkv; W_b; W_a]^T   (split epilogue: cols<2048 -> qkv_raw, else bg_raw)
    gemm_bt_bf16<<<dim3(NEXT/128, T_LEN/128), blk, 0, stream>>>(
        T_LEN, NEXT, DIM, x_bf, Wqkvba_bf, qkv_raw, bg_raw, CONV_DIM);
    // 2) z = x @ W_z^T  (overwrites Wqkvba region)
    gemm_bt_bf16<<<dim3(VAL_DIM/128, T_LEN/128), blk, 0, stream>>>(
        T_LEN, VAL_DIM, DIM, x_bf, Wz_bf, z_buf, z_buf, VAL_DIM);
    // 3) beta/g from bg_raw cols: 0..15 beta, 16..31 g
    betag_apply_kernel<<<dim3(T_LEN*32/256), blk, 0, stream>>>(bg_raw, dt_b, A_log, beta, g_buf);
    // 4) causal depthwise conv + silu
    conv_silu_kernel<<<dim3(CONV_DIM/256, T_LEN), blk, 0, stream>>>(qkv_raw, conv_w, qkv_act);
    // 5) phase 1: WY factors
    phase1_kernel<<<dim3(NV*NCHUNK), blk, 0, stream>>>(
        qkv_act, g_buf, beta, PT_all, B_all, RT_all, Oin_all);
    // 6) phase 2: sequential chunk recurrence
    phase2_kernel<<<dim3(NV*4), blk, 0, stream>>>(PT_all, B_all, RT_all, Oin_all, y_buf);
    // 7) RMSNorm + gate -> bf16
    rmsnorm_gate_kernel<<<dim3(T_LEN*NV/4), blk, 0, stream>>>(y_buf, z_buf, nw, yn_bf);
    f32_to_bf16_kernel<<<dim3(1024), blk, 0, stream>>>(W_out, Wout_bf);
    // 8) out = yn @ W_out^T
    gemm_bt_bf16<<<dim3(DIM/128, T_LEN/128), blk, 0, stream>>>(
        T_LEN, DIM, VAL_DIM, yn_bf, Wout_bf, out, out, DIM);
}